// Round 7
// baseline (1923.776 us; speedup 1.0000x reference)
//
#include <hip/hip_runtime.h>

// B=16, C=2048, T=128, ID=32, NC=16, CD=32, GD=32, OUT=96, GIN=192
// fp32 everywhere. ws: ext @0 (2,097,152) | ge @2097152 (1,048,576) |
// wraw @3145728 (589,824) | m2 @3735552 (294,912)  = 16.1 MB total.
//
// ADJACENCY SEMANTICS (the round-6 bug): neg = NEG*eye is a MATRIX.
//   jnp.where(adj <= 0, neg, adj) maps off-diagonal entries with
//   relu(s)==0 to logit 0.0 (softmax weight exp(0)=1), and ONLY the
//   diagonal to -1e9 (weight 0). So per row:
//     weight(m) = 0        if m == o
//                 exp(s)   if s > 0
//                 1        if s <= 0
// No max-subtraction needed: logits in {0} U (0, ~0.01].

// ---------------------------------------------------------------------------
// k1: per-row features. One block (128 threads) per row r = b*2048+c.
// ---------------------------------------------------------------------------
__global__ __launch_bounds__(128) void k1_simple(
    const float* __restrict__ x, const float* __restrict__ id_emb,
    const float* __restrict__ w1, const float* __restrict__ b1,
    const float* __restrict__ w2, const float* __restrict__ b2,
    const float* __restrict__ ce, const float* __restrict__ wic,
    const float* __restrict__ bic, const float* __restrict__ wg,
    const float* __restrict__ bg, float* __restrict__ ext,
    float* __restrict__ geo)
{
    __shared__ float sx[128];
    __shared__ float sh[64];
    __shared__ float sid[32];
    __shared__ float sic[32];
    __shared__ float sp[16];
    __shared__ float scl[32];

    const int r = blockIdx.x;
    const int c = r & 2047;
    const int t = threadIdx.x;

    sx[t] = x[r * 128 + t];
    __syncthreads();

    if (t < 64) {
        float a = b1[t];
        for (int k = 0; k < 128; ++k) a = fmaf(sx[k], w1[k * 64 + t], a);
        sh[t] = fmaxf(a, 0.f);
    }
    __syncthreads();

    if (t < 32) {
        float a = b2[t];
        for (int k = 0; k < 64; ++k) a = fmaf(sh[k], w2[k * 32 + t], a);
        float ide = id_emb[c * 32 + t] + a;
        sid[t] = ide;
        ext[r * 64 + t] = ide;
    }
    __syncthreads();

    if (t < 32) {
        float a = bic[t];
        for (int k = 0; k < 32; ++k) a = fmaf(sid[k], wic[k * 32 + t], a);
        sic[t] = a;
    }
    __syncthreads();

    if (t < 16) {
        float a = 0.f;
        for (int k = 0; k < 32; ++k) a = fmaf(sic[k], ce[t * 32 + k], a);
        sp[t] = a;
    }
    __syncthreads();

    if (t == 0) {
        float mx = sp[0];
        for (int n = 1; n < 16; ++n) mx = fmaxf(mx, sp[n]);
        float ss = 0.f;
        for (int n = 0; n < 16; ++n) { float e = __expf(sp[n] - mx); sp[n] = e; ss += e; }
        float inv = 1.f / ss;
        for (int n = 0; n < 16; ++n) sp[n] *= inv;
    }
    __syncthreads();

    if (t < 32) {
        float a = 0.f;
        for (int n = 0; n < 16; ++n) a = fmaf(sp[n], ce[n * 32 + t], a);
        scl[t] = a;
        ext[r * 64 + 32 + t] = a;
    }
    __syncthreads();

    if (t < 32) {
        float a = bg[t];
        for (int k = 0; k < 32; ++k) a = fmaf(sid[k], wg[k * 32 + t], a);
        for (int k = 0; k < 32; ++k) a = fmaf(scl[k], wg[(32 + k) * 32 + t], a);
        geo[r * 32 + t] = a;
    }
}

// ---------------------------------------------------------------------------
// k2: fused adjacency+softmax+aggregation+context-contribution.
// One block (256 thr) per (o-tile of 64 rows, batch). Flash-style loop over
// m-tiles of 32. V row = [x(128)|ext(64)]. Weight per the header comment.
// Epilogue: atomicAdd of agg-tile^T @ cw-tile into wraw.
// ---------------------------------------------------------------------------
__global__ __launch_bounds__(256) void k2_fused(
    const float* __restrict__ x, const float* __restrict__ ext,
    const float* __restrict__ ge, const float* __restrict__ cw,
    float* __restrict__ wraw)
{
    __shared__ float smem[12352];
    __shared__ float slp[256];
    __shared__ float sinv[64];
    float* sK = smem;            // [32][32]
    float* sV = smem + 1024;     // [32][192]
    float* se = smem + 7168;     // [64][36]

    const int t  = threadIdx.x;
    const int b  = blockIdx.y;
    const int o0 = blockIdx.x * 64;
    const float* geb = ge + b * 2048 * 32;
    const float* xb  = x + b * 2048 * 128;
    const float* eb  = ext + b * 2048 * 64;

    const int sr = t & 63;
    const int mg = t >> 6;
    const int pr = t >> 2;
    const int cb = (t & 3) * 48;

    float q[32];
    {
        const float4* qr = (const float4*)(geb + (o0 + sr) * 32);
        #pragma unroll
        for (int i = 0; i < 8; ++i) {
            float4 v = qr[i];
            q[i * 4 + 0] = v.x; q[i * 4 + 1] = v.y;
            q[i * 4 + 2] = v.z; q[i * 4 + 3] = v.w;
        }
    }

    float acc[48];
    #pragma unroll
    for (int j = 0; j < 48; ++j) acc[j] = 0.f;
    float lp = 0.f;

    for (int m0 = 0; m0 < 2048; m0 += 32) {
        ((float4*)sK)[t] = ((const float4*)(geb + m0 * 32))[t];
        {
            const float4* xb4 = (const float4*)xb;
            #pragma unroll
            for (int k = 0; k < 4; ++k) {
                int i = t + k * 256;
                int mm = i >> 5, c4 = i & 31;
                ((float4*)(sV + mm * 192))[c4] = xb4[(m0 + mm) * 32 + c4];
            }
        }
        {
            const float4* eb4 = (const float4*)eb;
            #pragma unroll
            for (int k = 0; k < 2; ++k) {
                int i = t + k * 256;
                int mm = i >> 4, c4 = i & 15;
                ((float4*)(sV + mm * 192 + 128))[c4] = eb4[(m0 + mm) * 16 + c4];
            }
        }
        __syncthreads();
        #pragma unroll
        for (int j = 0; j < 8; ++j) {
            int mm = mg * 8 + j;
            const float* kr = sK + mm * 32;
            float s = 0.f;
            #pragma unroll
            for (int k = 0; k < 32; ++k) s = fmaf(q[k], kr[k], s);
            int gm = m0 + mm;
            // CORRECT SEMANTICS: diag->0; s>0 -> exp(s); s<=0 -> 1
            float e = (gm == o0 + sr) ? 0.f : ((s > 0.f) ? __expf(s) : 1.f);
            se[sr * 36 + mm] = e;
            lp += e;
        }
        __syncthreads();
        for (int mm = 0; mm < 32; ++mm) {
            float e = se[pr * 36 + mm];
            const float* vr = sV + mm * 192 + cb;
            #pragma unroll
            for (int j = 0; j < 48; ++j) acc[j] = fmaf(e, vr[j], acc[j]);
        }
        __syncthreads();
    }

    slp[mg * 64 + sr] = lp;
    __syncthreads();
    if (t < 64) {
        float l = slp[t] + slp[64 + t] + slp[128 + t] + slp[192 + t];
        sinv[t] = 1.f / l;
    }
    __syncthreads();

    {
        float inv = sinv[pr];
        float* ar = smem + pr * 193 + cb;
        #pragma unroll
        for (int j = 0; j < 48; ++j) ar[j] = acc[j] * inv;
    }
    __syncthreads();

    {
        const int dg = t >> 4, lg = t & 15;
        const int d0t = dg * 12, l0t = lg * 12;
        float acc2[12][12];
        #pragma unroll
        for (int i = 0; i < 12; ++i)
            #pragma unroll
            for (int j = 0; j < 12; ++j) acc2[i][j] = 0.f;
        for (int oo = 0; oo < 64; ++oo) {
            float a[12], cc[12];
            const float* ar = smem + oo * 193 + d0t;
            const float* cr = cw + (o0 + oo) * 192 + l0t;
            #pragma unroll
            for (int i = 0; i < 12; ++i) a[i] = ar[i];
            #pragma unroll
            for (int j = 0; j < 12; ++j) cc[j] = cr[j];
            #pragma unroll
            for (int i = 0; i < 12; ++i)
                #pragma unroll
                for (int j = 0; j < 12; ++j)
                    acc2[i][j] = fmaf(a[i], cc[j], acc2[i][j]);
        }
        float* wb = wraw + b * 36864;
        #pragma unroll
        for (int i = 0; i < 12; ++i)
            #pragma unroll
            for (int j = 0; j < 12; ++j)
                atomicAdd(&wb[(d0t + i) * 192 + l0t + j], acc2[i][j]);
    }
}

// ---------------------------------------------------------------------------
__global__ __launch_bounds__(256) void k3a_tanh(float* __restrict__ wraw)
{
    int i = blockIdx.x * 256 + threadIdx.x;
    wraw[i] = tanhf(wraw[i]);
}

// ---------------------------------------------------------------------------
__global__ __launch_bounds__(192) void k3b_m2(
    const float* __restrict__ wmat, const float* __restrict__ wl,
    float* __restrict__ m2)
{
    const int t = threadIdx.x;
    const int b = blockIdx.y;
    const int d = blockIdx.x * 2 + (t / 96);
    const int l = t % 96;
    const float* wrow = wmat + b * 36864 + d * 192;
    float acc = wl[d * 96 + l];
    for (int k = 0; k < 192; ++k)
        acc = fmaf(wrow[k], wl[k * 96 + l], acc);
    m2[b * 18432 + d * 96 + l] = acc;
}

// ---------------------------------------------------------------------------
__global__ __launch_bounds__(96) void k4_simple(
    const float* __restrict__ x, const float* __restrict__ ext,
    const float* __restrict__ m2, const float* __restrict__ bl,
    float* __restrict__ out)
{
    __shared__ float sx[128];
    __shared__ float sxe[64];
    const int r = blockIdx.x;
    const int b = r >> 11;
    const int t = threadIdx.x;
    for (int i = t; i < 128; i += 96) sx[i] = x[r * 128 + i];
    if (t < 64) sxe[t] = ext[r * 64 + t];
    __syncthreads();
    const float* mb = m2 + b * 18432;
    float a = bl[t];
    for (int k = 0; k < 128; ++k) a = fmaf(sx[k], mb[k * 96 + t], a);
    for (int k = 0; k < 64; ++k) a = fmaf(sxe[k], mb[(128 + k) * 96 + t], a);
    out[r * 96 + t] = a;
}

// ---------------------------------------------------------------------------
extern "C" void kernel_launch(void* const* d_in, const int* in_sizes, int n_in,
                              void* d_out, int out_size, void* d_ws, size_t ws_size,
                              hipStream_t stream) {
    const float* x      = (const float*)d_in[0];
    const float* id_emb = (const float*)d_in[1];
    const float* w1     = (const float*)d_in[2];
    const float* b1     = (const float*)d_in[3];
    const float* w2     = (const float*)d_in[4];
    const float* b2     = (const float*)d_in[5];
    const float* ce     = (const float*)d_in[6];
    const float* wic    = (const float*)d_in[7];
    const float* bic    = (const float*)d_in[8];
    const float* wg     = (const float*)d_in[9];
    const float* bg     = (const float*)d_in[10];
    const float* cw     = (const float*)d_in[11];
    const float* wl     = (const float*)d_in[12];
    const float* bl     = (const float*)d_in[13];
    float* out = (float*)d_out;

    float* ws   = (float*)d_ws;
    float* ext  = ws;               // 2,097,152 floats
    float* ge   = ws + 2097152;     // 1,048,576
    float* wraw = ws + 3145728;     //   589,824
    float* m2   = ws + 3735552;     //   294,912

    hipMemsetAsync(wraw, 0, 589824 * sizeof(float), stream);
    hipLaunchKernelGGL(k1_simple, dim3(32768), dim3(128), 0, stream,
                       x, id_emb, w1, b1, w2, b2, ce, wic, bic, wg, bg, ext, ge);
    hipLaunchKernelGGL(k2_fused, dim3(32, 16), dim3(256), 0, stream,
                       x, ext, ge, cw, wraw);
    hipLaunchKernelGGL(k3a_tanh, dim3(2304), dim3(256), 0, stream, wraw);
    hipLaunchKernelGGL(k3b_m2, dim3(96, 16), dim3(192), 0, stream,
                       wraw, wl, m2);
    hipLaunchKernelGGL(k4_simple, dim3(32768), dim3(96), 0, stream,
                       x, ext, m2, bl, out);
}

// Round 8
// 1454.111 us; speedup vs baseline: 1.3230x; 1.3230x over previous
//
#include <hip/hip_runtime.h>

// B=16, C=2048, T=128, ID=32, NC=16, CD=32, GD=32, OUT=96, GIN=192
// fp32 everywhere. ws: ext @0 (2,097,152) | ge @2097152 (1,048,576) |
// wraw @3145728 (589,824) | m2 @3735552 (294,912)  = 16.1 MB total.
//
// ADJACENCY SEMANTICS: neg = NEG*eye is a MATRIX. Off-diagonal entries with
// relu(s)==0 get logit 0 (weight exp(0)=1); only the diagonal is -1e9.
//   weight(m) = 0 if m==o; exp(s) if s>0; 1 if s<=0.
// No max-subtraction needed: logits in {0} U (0,~0.01].

// ---------------------------------------------------------------------------
// k1: per-row features. One block (128 threads) per row r = b*2048+c.
// ---------------------------------------------------------------------------
__global__ __launch_bounds__(128) void k1_simple(
    const float* __restrict__ x, const float* __restrict__ id_emb,
    const float* __restrict__ w1, const float* __restrict__ b1,
    const float* __restrict__ w2, const float* __restrict__ b2,
    const float* __restrict__ ce, const float* __restrict__ wic,
    const float* __restrict__ bic, const float* __restrict__ wg,
    const float* __restrict__ bg, float* __restrict__ ext,
    float* __restrict__ geo)
{
    __shared__ float sx[128];
    __shared__ float sh[64];
    __shared__ float sid[32];
    __shared__ float sic[32];
    __shared__ float sp[16];
    __shared__ float scl[32];

    const int r = blockIdx.x;
    const int c = r & 2047;
    const int t = threadIdx.x;

    sx[t] = x[r * 128 + t];
    __syncthreads();

    if (t < 64) {
        float a = b1[t];
        for (int k = 0; k < 128; ++k) a = fmaf(sx[k], w1[k * 64 + t], a);
        sh[t] = fmaxf(a, 0.f);
    }
    __syncthreads();

    if (t < 32) {
        float a = b2[t];
        for (int k = 0; k < 64; ++k) a = fmaf(sh[k], w2[k * 32 + t], a);
        float ide = id_emb[c * 32 + t] + a;
        sid[t] = ide;
        ext[r * 64 + t] = ide;
    }
    __syncthreads();

    if (t < 32) {
        float a = bic[t];
        for (int k = 0; k < 32; ++k) a = fmaf(sid[k], wic[k * 32 + t], a);
        sic[t] = a;
    }
    __syncthreads();

    if (t < 16) {
        float a = 0.f;
        for (int k = 0; k < 32; ++k) a = fmaf(sic[k], ce[t * 32 + k], a);
        sp[t] = a;
    }
    __syncthreads();

    if (t == 0) {
        float mx = sp[0];
        for (int n = 1; n < 16; ++n) mx = fmaxf(mx, sp[n]);
        float ss = 0.f;
        for (int n = 0; n < 16; ++n) { float e = __expf(sp[n] - mx); sp[n] = e; ss += e; }
        float inv = 1.f / ss;
        for (int n = 0; n < 16; ++n) sp[n] *= inv;
    }
    __syncthreads();

    if (t < 32) {
        float a = 0.f;
        for (int n = 0; n < 16; ++n) a = fmaf(sp[n], ce[n * 32 + t], a);
        scl[t] = a;
        ext[r * 64 + 32 + t] = a;
    }
    __syncthreads();

    if (t < 32) {
        float a = bg[t];
        for (int k = 0; k < 32; ++k) a = fmaf(sid[k], wg[k * 32 + t], a);
        for (int k = 0; k < 32; ++k) a = fmaf(scl[k], wg[(32 + k) * 32 + t], a);
        geo[r * 32 + t] = a;
    }
}

// ---------------------------------------------------------------------------
// k2 v2: fused adjacency+softmax+aggregation+context-contribution.
// Block (256 thr) owns 64 o-rows of batch b. K-loop over m-tiles of 64.
// S phase: wave-per-row (sr=lane), 16 m's per thread, K rows broadcast.
// PV phase: 4x12 register tile per thread -> 16 b128 LDS per 192 FMAs.
// Epilogue: agg tile -> LDS (stride 193) -> atomicAdd agg^T @ cw into wraw.
// ---------------------------------------------------------------------------
__global__ __launch_bounds__(256) void k2_fused(
    const float* __restrict__ x, const float* __restrict__ ext,
    const float* __restrict__ ge, const float* __restrict__ cw,
    float* __restrict__ wraw)
{
    __shared__ float smem[18688];   // sK[64*32] | sV[64*192] | se[64*68]
    __shared__ float slp[256];
    __shared__ float sinv[64];
    float* sK = smem;               // 2048 floats
    float* sV = smem + 2048;        // 12288 floats
    float* se = smem + 14336;       // 4352 floats, row stride 68

    const int t  = threadIdx.x;
    const int b  = blockIdx.y;
    const int o0 = blockIdx.x * 64;
    const float* geb = ge + b * 2048 * 32;
    const float* xb  = x + b * 2048 * 128;
    const float* eb  = ext + b * 2048 * 64;

    // S-phase role
    const int sr = t & 63;          // o-row within tile (lane)
    const int mg = t >> 6;          // wave id: m-subrange [mg*16, +16)
    // PV-phase role: 4 rows x 12 cols
    const int rg = t >> 4;          // 0..15
    const int dg = t & 15;          // 0..15
    const int rbase = rg * 4;
    const int cbase = dg * 12;

    float q[32];
    {
        const float4* qr = (const float4*)(geb + (o0 + sr) * 32);
        #pragma unroll
        for (int i = 0; i < 8; ++i) {
            float4 v = qr[i];
            q[i * 4 + 0] = v.x; q[i * 4 + 1] = v.y;
            q[i * 4 + 2] = v.z; q[i * 4 + 3] = v.w;
        }
    }

    float acc[4][12];
    #pragma unroll
    for (int i = 0; i < 4; ++i)
        #pragma unroll
        for (int j = 0; j < 12; ++j) acc[i][j] = 0.f;
    float lp = 0.f;

    for (int m0 = 0; m0 < 2048; m0 += 64) {
        // stage K tile (64x32): 512 float4, 2 per thread
        {
            const float4* src = (const float4*)(geb + m0 * 32);
            float4* dst = (float4*)sK;
            dst[t] = src[t];
            dst[t + 256] = src[t + 256];
        }
        // stage V x-part (64x128): 2048 float4, 8 per thread
        {
            const float4* xb4 = (const float4*)xb;   // row = 32 float4
            #pragma unroll
            for (int kk = 0; kk < 8; ++kk) {
                int i = t + kk * 256;
                int mm = i >> 5, c4 = i & 31;
                ((float4*)(sV + mm * 192))[c4] = xb4[(m0 + mm) * 32 + c4];
            }
        }
        // stage V ext-part (64x64): 1024 float4, 4 per thread
        {
            const float4* eb4 = (const float4*)eb;   // row = 16 float4
            #pragma unroll
            for (int kk = 0; kk < 4; ++kk) {
                int i = t + kk * 256;
                int mm = i >> 4, c4 = i & 15;
                ((float4*)(sV + mm * 192 + 128))[c4] = eb4[(m0 + mm) * 16 + c4];
            }
        }
        __syncthreads();

        // S phase: 16 m entries per thread; kr row is wave-broadcast
        #pragma unroll
        for (int j = 0; j < 16; ++j) {
            int mm = mg * 16 + j;
            const float* kr = sK + mm * 32;
            float s = 0.f;
            #pragma unroll
            for (int k = 0; k < 32; ++k) s = fmaf(q[k], kr[k], s);
            int gm = m0 + mm;
            float e = (gm == o0 + sr) ? 0.f : ((s > 0.f) ? __expf(s) : 1.f);
            se[sr * 68 + mm] = e;
            lp += e;
        }
        __syncthreads();

        // PV phase: 16 sub-blocks of 4 mm each
        #pragma unroll 2
        for (int mb = 0; mb < 16; ++mb) {
            float4 e0 = *(const float4*)(se + (rbase + 0) * 68 + mb * 4);
            float4 e1 = *(const float4*)(se + (rbase + 1) * 68 + mb * 4);
            float4 e2 = *(const float4*)(se + (rbase + 2) * 68 + mb * 4);
            float4 e3 = *(const float4*)(se + (rbase + 3) * 68 + mb * 4);
            const float* vbase = sV + (mb * 4) * 192 + cbase;
            #pragma unroll
            for (int u = 0; u < 4; ++u) {
                float v[12];
                const float* vr = vbase + u * 192;
                #pragma unroll
                for (int j = 0; j < 12; ++j) v[j] = vr[j];
                float w0 = (&e0.x)[u];
                float w1v = (&e1.x)[u];
                float w2v = (&e2.x)[u];
                float w3 = (&e3.x)[u];
                #pragma unroll
                for (int j = 0; j < 12; ++j) {
                    acc[0][j] = fmaf(w0, v[j], acc[0][j]);
                    acc[1][j] = fmaf(w1v, v[j], acc[1][j]);
                    acc[2][j] = fmaf(w2v, v[j], acc[2][j]);
                    acc[3][j] = fmaf(w3, v[j], acc[3][j]);
                }
            }
        }
        __syncthreads();
    }

    // softmax denominators: 4 wave-partials per row
    slp[mg * 64 + sr] = lp;
    __syncthreads();
    if (t < 64) {
        float l = slp[t] + slp[64 + t] + slp[128 + t] + slp[192 + t];
        sinv[t] = 1.f / l;
    }
    __syncthreads();

    // write agg tile (64x192) into smem, row stride 193 (aliases sK/sV)
    #pragma unroll
    for (int i = 0; i < 4; ++i) {
        float inv = sinv[rbase + i];
        float* ar = smem + (rbase + i) * 193 + cbase;
        #pragma unroll
        for (int j = 0; j < 12; ++j) ar[j] = acc[i][j] * inv;
    }
    __syncthreads();

    // contribution[d][l] = sum_oo agg[oo][d] * cw[o0+oo][l]; 12x12 per thread
    {
        const int dgi = t >> 4, lg = t & 15;
        const int d0t = dgi * 12, l0t = lg * 12;
        float acc2[12][12];
        #pragma unroll
        for (int i = 0; i < 12; ++i)
            #pragma unroll
            for (int j = 0; j < 12; ++j) acc2[i][j] = 0.f;
        for (int oo = 0; oo < 64; ++oo) {
            float a[12], cc[12];
            const float* ar = smem + oo * 193 + d0t;
            const float* cr = cw + (o0 + oo) * 192 + l0t;
            #pragma unroll
            for (int i = 0; i < 12; ++i) a[i] = ar[i];
            #pragma unroll
            for (int j = 0; j < 12; ++j) cc[j] = cr[j];
            #pragma unroll
            for (int i = 0; i < 12; ++i)
                #pragma unroll
                for (int j = 0; j < 12; ++j)
                    acc2[i][j] = fmaf(a[i], cc[j], acc2[i][j]);
        }
        float* wb = wraw + b * 36864;
        #pragma unroll
        for (int i = 0; i < 12; ++i)
            #pragma unroll
            for (int j = 0; j < 12; ++j)
                atomicAdd(&wb[(d0t + i) * 192 + l0t + j], acc2[i][j]);
    }
}

// ---------------------------------------------------------------------------
__global__ __launch_bounds__(256) void k3a_tanh(float* __restrict__ wraw)
{
    int i = blockIdx.x * 256 + threadIdx.x;
    wraw[i] = tanhf(wraw[i]);
}

// ---------------------------------------------------------------------------
__global__ __launch_bounds__(192) void k3b_m2(
    const float* __restrict__ wmat, const float* __restrict__ wl,
    float* __restrict__ m2)
{
    const int t = threadIdx.x;
    const int b = blockIdx.y;
    const int d = blockIdx.x * 2 + (t / 96);
    const int l = t % 96;
    const float* wrow = wmat + b * 36864 + d * 192;
    float acc = wl[d * 96 + l];
    for (int k = 0; k < 192; ++k)
        acc = fmaf(wrow[k], wl[k * 96 + l], acc);
    m2[b * 18432 + d * 96 + l] = acc;
}

// ---------------------------------------------------------------------------
__global__ __launch_bounds__(96) void k4_simple(
    const float* __restrict__ x, const float* __restrict__ ext,
    const float* __restrict__ m2, const float* __restrict__ bl,
    float* __restrict__ out)
{
    __shared__ float sx[128];
    __shared__ float sxe[64];
    const int r = blockIdx.x;
    const int b = r >> 11;
    const int t = threadIdx.x;
    for (int i = t; i < 128; i += 96) sx[i] = x[r * 128 + i];
    if (t < 64) sxe[t] = ext[r * 64 + t];
    __syncthreads();
    const float* mb = m2 + b * 18432;
    float a = bl[t];
    for (int k = 0; k < 128; ++k) a = fmaf(sx[k], mb[k * 96 + t], a);
    for (int k = 0; k < 64; ++k) a = fmaf(sxe[k], mb[(128 + k) * 96 + t], a);
    out[r * 96 + t] = a;
}

// ---------------------------------------------------------------------------
extern "C" void kernel_launch(void* const* d_in, const int* in_sizes, int n_in,
                              void* d_out, int out_size, void* d_ws, size_t ws_size,
                              hipStream_t stream) {
    const float* x      = (const float*)d_in[0];
    const float* id_emb = (const float*)d_in[1];
    const float* w1     = (const float*)d_in[2];
    const float* b1     = (const float*)d_in[3];
    const float* w2     = (const float*)d_in[4];
    const float* b2     = (const float*)d_in[5];
    const float* ce     = (const float*)d_in[6];
    const float* wic    = (const float*)d_in[7];
    const float* bic    = (const float*)d_in[8];
    const float* wg     = (const float*)d_in[9];
    const float* bg     = (const float*)d_in[10];
    const float* cw     = (const float*)d_in[11];
    const float* wl     = (const float*)d_in[12];
    const float* bl     = (const float*)d_in[13];
    float* out = (float*)d_out;

    float* ws   = (float*)d_ws;
    float* ext  = ws;               // 2,097,152 floats
    float* ge   = ws + 2097152;     // 1,048,576
    float* wraw = ws + 3145728;     //   589,824
    float* m2   = ws + 3735552;     //   294,912

    hipMemsetAsync(wraw, 0, 589824 * sizeof(float), stream);
    hipLaunchKernelGGL(k1_simple, dim3(32768), dim3(128), 0, stream,
                       x, id_emb, w1, b1, w2, b2, ce, wic, bic, wg, bg, ext, ge);
    hipLaunchKernelGGL(k2_fused, dim3(32, 16), dim3(256), 0, stream,
                       x, ext, ge, cw, wraw);
    hipLaunchKernelGGL(k3a_tanh, dim3(2304), dim3(256), 0, stream, wraw);
    hipLaunchKernelGGL(k3b_m2, dim3(96, 16), dim3(192), 0, stream,
                       wraw, wl, m2);
    hipLaunchKernelGGL(k4_simple, dim3(32768), dim3(96), 0, stream,
                       x, ext, m2, bl, out);
}

// Round 9
// 1284.038 us; speedup vs baseline: 1.4982x; 1.1325x over previous
//
#include <hip/hip_runtime.h>
#include <hip/hip_bf16.h>

// B=16, C=2048, T=128, ID=32, NC=16, CD=32, GD=32, OUT=96, GIN=192
// ws (floats): vt(bf16, 16*192*2048 = 3,145,728 f-equiv) @0 | ge @3145728
// (1,048,576) | wraw @4194304 (589,824) | m2 @4784128 (294,912) |
// sumv @5079040 (3,072)  => 20.3 MB total.
//
// ADJACENCY SEMANTICS: weight(m) = 0 if m==o; exp(s) if s>0; 1 if s<=0.
// Decomposition for MFMA: d = weight-1 (d=-1 diag, exp(s)-1 if s>0, else 0).
// agg_unnorm = sumV + MFMA(d,V);  l = 2048 + sum(d).  All V in bf16 (VT).

typedef __attribute__((ext_vector_type(8))) short short8;
typedef __attribute__((ext_vector_type(16))) float f32x16;

__device__ __forceinline__ unsigned short f2bf(float f) {
    __hip_bfloat16 h = __float2bfloat16(f);
    return *reinterpret_cast<unsigned short*>(&h);
}
__device__ __forceinline__ float bf2f(unsigned short u) {
    __hip_bfloat16 h = *reinterpret_cast<__hip_bfloat16*>(&u);
    return __bfloat162float(h);
}

// ---------------------------------------------------------------------------
// k0: transpose x (fp32 [b][m][128]) -> VT bf16 [b][ch][m] for ch 0..127.
// ---------------------------------------------------------------------------
__global__ __launch_bounds__(256) void k0_transpose_x(
    const float* __restrict__ x, unsigned short* __restrict__ vt)
{
    __shared__ float sT[64 * 133];
    const int t = threadIdx.x;
    const int m0 = blockIdx.x * 64;
    const int b = blockIdx.y;
    const float* xb = x + (size_t)b * 2048 * 128;
    #pragma unroll
    for (int kk = 0; kk < 8; ++kk) {
        int i = t + kk * 256;               // 2048 float4 units
        int mm = i >> 5, q4 = i & 31;
        float4 v = ((const float4*)(xb + (size_t)(m0 + mm) * 128))[q4];
        float* d = sT + mm * 133 + q4 * 4;
        d[0] = v.x; d[1] = v.y; d[2] = v.z; d[3] = v.w;
    }
    __syncthreads();
    const int mp = t & 31;                  // m-pair
    const int ch0 = t >> 5;                 // 0..7
    #pragma unroll
    for (int pass = 0; pass < 16; ++pass) {
        int ch = ch0 + pass * 8;
        unsigned int u0 = f2bf(sT[(2 * mp) * 133 + ch]);
        unsigned int u1 = f2bf(sT[(2 * mp + 1) * 133 + ch]);
        *((unsigned int*)(vt + (size_t)(b * 192 + ch) * 2048 + m0) + mp) =
            u0 | (u1 << 16);
    }
}

// ---------------------------------------------------------------------------
// k1: per-row features. One block (128 thr) per row r. Writes ge (fp32) and
// VT channels 128..191 (id_e | cl) as bf16 (scattered u16; L2 merges).
// ---------------------------------------------------------------------------
__global__ __launch_bounds__(128) void k1_simple(
    const float* __restrict__ x, const float* __restrict__ id_emb,
    const float* __restrict__ w1, const float* __restrict__ b1,
    const float* __restrict__ w2, const float* __restrict__ b2,
    const float* __restrict__ ce, const float* __restrict__ wic,
    const float* __restrict__ bic, const float* __restrict__ wg,
    const float* __restrict__ bg, unsigned short* __restrict__ vt,
    float* __restrict__ geo)
{
    __shared__ float sx[128];
    __shared__ float sh[64];
    __shared__ float sid[32];
    __shared__ float sic[32];
    __shared__ float sp[16];
    __shared__ float scl[32];

    const int r = blockIdx.x;
    const int b = r >> 11;
    const int c = r & 2047;
    const int t = threadIdx.x;

    sx[t] = x[(size_t)r * 128 + t];
    __syncthreads();

    if (t < 64) {
        float a = b1[t];
        for (int k = 0; k < 128; ++k) a = fmaf(sx[k], w1[k * 64 + t], a);
        sh[t] = fmaxf(a, 0.f);
    }
    __syncthreads();

    if (t < 32) {
        float a = b2[t];
        for (int k = 0; k < 64; ++k) a = fmaf(sh[k], w2[k * 32 + t], a);
        float ide = id_emb[c * 32 + t] + a;
        sid[t] = ide;
        vt[(size_t)(b * 192 + 128 + t) * 2048 + c] = f2bf(ide);
    }
    __syncthreads();

    if (t < 32) {
        float a = bic[t];
        for (int k = 0; k < 32; ++k) a = fmaf(sid[k], wic[k * 32 + t], a);
        sic[t] = a;
    }
    __syncthreads();

    if (t < 16) {
        float a = 0.f;
        for (int k = 0; k < 32; ++k) a = fmaf(sic[k], ce[t * 32 + k], a);
        sp[t] = a;
    }
    __syncthreads();

    if (t == 0) {
        float mx = sp[0];
        for (int n = 1; n < 16; ++n) mx = fmaxf(mx, sp[n]);
        float ss = 0.f;
        for (int n = 0; n < 16; ++n) { float e = __expf(sp[n] - mx); sp[n] = e; ss += e; }
        float inv = 1.f / ss;
        for (int n = 0; n < 16; ++n) sp[n] *= inv;
    }
    __syncthreads();

    if (t < 32) {
        float a = 0.f;
        for (int n = 0; n < 16; ++n) a = fmaf(sp[n], ce[n * 32 + t], a);
        scl[t] = a;
        vt[(size_t)(b * 192 + 160 + t) * 2048 + c] = f2bf(a);
    }
    __syncthreads();

    if (t < 32) {
        float a = bg[t];
        for (int k = 0; k < 32; ++k) a = fmaf(sid[k], wg[k * 32 + t], a);
        for (int k = 0; k < 32; ++k) a = fmaf(scl[k], wg[(32 + k) * 32 + t], a);
        geo[(size_t)r * 32 + t] = a;
    }
}

// ---------------------------------------------------------------------------
// k1b: sumV[b][ch] = sum_m VT[b][ch][m] (fp32 accumulate of bf16).
// ---------------------------------------------------------------------------
__global__ __launch_bounds__(256) void k1b_sumv(
    const unsigned short* __restrict__ vt, float* __restrict__ sumv)
{
    __shared__ float red[256];
    const int ch = blockIdx.x, b = blockIdx.y, t = threadIdx.x;
    const unsigned short* row = vt + (size_t)(b * 192 + ch) * 2048;
    float a = 0.f;
    #pragma unroll
    for (int j = 0; j < 8; ++j) a += bf2f(row[t * 8 + j]);
    red[t] = a; __syncthreads();
    for (int off = 128; off > 0; off >>= 1) {
        if (t < off) red[t] += red[t + off];
        __syncthreads();
    }
    if (t == 0) sumv[b * 192 + ch] = red[0];
}

// ---------------------------------------------------------------------------
// k2: S-phase (VALU fp32) -> d-weights bf16 in LDS -> PV via MFMA 32x32x16
// bf16 -> epilogue (sumV + D)/l -> cw contraction (VALU) -> atomicAdd wraw.
// Block (256 thr = 4 waves) owns 64 o-rows x 192 ch of batch b; m-tiles of 64.
// Wave w: o-sub (w&1)*32, ch-half (w>>1)*96 (3 32x32 C-frags).
// ---------------------------------------------------------------------------
__global__ __launch_bounds__(256) void k2_fused(
    const float* __restrict__ ge, const unsigned short* __restrict__ vt,
    const float* __restrict__ cw, const float* __restrict__ sumv,
    float* __restrict__ wraw)
{
    __shared__ float s_agg[64 * 193];   // 12352 f; phase-1 arrays alias inside
    __shared__ float slp[256];
    __shared__ float sinv[64];
    __shared__ float s_sum[192];
    float* sK = s_agg;                                        // [64][32] fp32
    unsigned short* sVt = (unsigned short*)(s_agg + 2048);    // [192][72] bf16
    unsigned short* dw  = (unsigned short*)(s_agg + 8960);    // [64][72] bf16

    const int t = threadIdx.x;
    const int b = blockIdx.y;
    const int o0 = blockIdx.x * 64;
    const float* geb = ge + (size_t)b * 2048 * 32;
    const unsigned short* vtb = vt + (size_t)b * 192 * 2048;

    const int sr = t & 63;          // lane: o-row for S phase
    const int mg = t >> 6;          // wave id
    const int col = sr & 31;
    const int grp = sr >> 5;
    const int orow0 = (mg & 1) * 32;
    const int dbase = (mg >> 1) * 96;

    if (t < 192) s_sum[t] = sumv[b * 192 + t];

    float q[32];
    {
        const float4* qr = (const float4*)(geb + (size_t)(o0 + sr) * 32);
        #pragma unroll
        for (int i = 0; i < 8; ++i) {
            float4 v = qr[i];
            q[i*4+0] = v.x; q[i*4+1] = v.y; q[i*4+2] = v.z; q[i*4+3] = v.w;
        }
    }

    f32x16 acc0, acc1, acc2;
    #pragma unroll
    for (int i = 0; i < 16; ++i) { acc0[i] = 0.f; acc1[i] = 0.f; acc2[i] = 0.f; }
    float lp = 0.f;

    for (int m0 = 0; m0 < 2048; m0 += 64) {
        // stage sK (ge tile, fp32): 512 float4
        {
            const float4* src = (const float4*)(geb + (size_t)m0 * 32);
            float4* dst = (float4*)sK;
            dst[t] = src[t];
            dst[t + 256] = src[t + 256];
        }
        // stage sVt (192ch x 64m bf16): 1536 chunks of 16B
        #pragma unroll
        for (int kk = 0; kk < 6; ++kk) {
            int i = t + kk * 256;
            int ch = i >> 3, m8 = i & 7;
            short8 v = *(const short8*)(vtb + (size_t)ch * 2048 + m0 + m8 * 8);
            *(short8*)(sVt + ch * 72 + m8 * 8) = v;
        }
        __syncthreads();

        // S phase: d = weight-1; write bf16 pairs into dw[sr][m]
        #pragma unroll
        for (int jj = 0; jj < 16; jj += 2) {
            float dvp[2];
            #pragma unroll
            for (int u = 0; u < 2; ++u) {
                int mm = mg * 16 + jj + u;
                const float4* kr4 = (const float4*)(sK + mm * 32);
                float s = 0.f;
                #pragma unroll
                for (int c4 = 0; c4 < 8; ++c4) {
                    float4 kv = kr4[c4];
                    s = fmaf(q[c4*4+0], kv.x, s);
                    s = fmaf(q[c4*4+1], kv.y, s);
                    s = fmaf(q[c4*4+2], kv.z, s);
                    s = fmaf(q[c4*4+3], kv.w, s);
                }
                int gm = m0 + mm;
                float dv = (gm == o0 + sr) ? -1.f
                         : ((s > 0.f) ? (__expf(s) - 1.f) : 0.f);
                lp += dv;
                dvp[u] = dv;
            }
            *(unsigned int*)(dw + sr * 72 + mg * 16 + jj) =
                (unsigned int)f2bf(dvp[0]) | ((unsigned int)f2bf(dvp[1]) << 16);
        }
        __syncthreads();

        // PV phase: 4 MFMA K-steps (K=16)
        #pragma unroll
        for (int ks = 0; ks < 4; ++ks) {
            short8 A  = *(const short8*)(dw + (orow0 + col) * 72 + ks * 16 + grp * 8);
            short8 B0 = *(const short8*)(sVt + (dbase + col) * 72 + ks * 16 + grp * 8);
            short8 B1 = *(const short8*)(sVt + (dbase + 32 + col) * 72 + ks * 16 + grp * 8);
            short8 B2 = *(const short8*)(sVt + (dbase + 64 + col) * 72 + ks * 16 + grp * 8);
            acc0 = __builtin_amdgcn_mfma_f32_32x32x16_bf16(A, B0, acc0, 0, 0, 0);
            acc1 = __builtin_amdgcn_mfma_f32_32x32x16_bf16(A, B1, acc1, 0, 0, 0);
            acc2 = __builtin_amdgcn_mfma_f32_32x32x16_bf16(A, B2, acc2, 0, 0, 0);
        }
        __syncthreads();
    }

    // denominators: l = 2048 + sum(d)  (d_diag = -1 folds the -V_o term)
    slp[mg * 64 + sr] = lp;
    __syncthreads();
    if (t < 64) {
        float l = 2048.f + slp[t] + slp[64 + t] + slp[128 + t] + slp[192 + t];
        sinv[t] = 1.f / l;
    }
    __syncthreads();

    // epilogue: agg = (sumV + D) / l -> s_agg (overwrites phase-1 arrays)
    {
        f32x16 av[3] = {acc0, acc1, acc2};
        #pragma unroll
        for (int n = 0; n < 3; ++n) {
            int chn = dbase + n * 32 + col;
            float sv = s_sum[chn];
            #pragma unroll
            for (int r = 0; r < 16; ++r) {
                int ol = orow0 + (r & 3) + 8 * (r >> 2) + 4 * grp;
                s_agg[ol * 193 + chn] = (sv + av[n][r]) * sinv[ol];
            }
        }
    }
    __syncthreads();

    // contribution[d][l] = sum_oo agg[oo][d]*cw[o0+oo][l]; 12x12 per thread
    {
        const int dgi = t >> 4, lg = t & 15;
        const int d0t = dgi * 12, l0t = lg * 12;
        float acc2r[12][12];
        #pragma unroll
        for (int i = 0; i < 12; ++i)
            #pragma unroll
            for (int j = 0; j < 12; ++j) acc2r[i][j] = 0.f;
        for (int oo = 0; oo < 64; ++oo) {
            float a[12], cc[12];
            const float* ar = s_agg + oo * 193 + d0t;
            const float* cr = cw + (size_t)(o0 + oo) * 192 + l0t;
            #pragma unroll
            for (int i = 0; i < 12; ++i) a[i] = ar[i];
            #pragma unroll
            for (int j = 0; j < 12; ++j) cc[j] = cr[j];
            #pragma unroll
            for (int i = 0; i < 12; ++i)
                #pragma unroll
                for (int j = 0; j < 12; ++j)
                    acc2r[i][j] = fmaf(a[i], cc[j], acc2r[i][j]);
        }
        float* wb = wraw + (size_t)b * 36864;
        #pragma unroll
        for (int i = 0; i < 12; ++i)
            #pragma unroll
            for (int j = 0; j < 12; ++j)
                atomicAdd(&wb[(d0t + i) * 192 + l0t + j], acc2r[i][j]);
    }
}

// ---------------------------------------------------------------------------
__global__ __launch_bounds__(256) void k3a_tanh(float* __restrict__ wraw)
{
    int i = blockIdx.x * 256 + threadIdx.x;
    wraw[i] = tanhf(wraw[i]);
}

// ---------------------------------------------------------------------------
__global__ __launch_bounds__(192) void k3b_m2(
    const float* __restrict__ wmat, const float* __restrict__ wl,
    float* __restrict__ m2)
{
    const int t = threadIdx.x;
    const int b = blockIdx.y;
    const int d = blockIdx.x * 2 + (t / 96);
    const int l = t % 96;
    const float* wrow = wmat + (size_t)b * 36864 + d * 192;
    float acc = wl[d * 96 + l];
    for (int k = 0; k < 192; ++k)
        acc = fmaf(wrow[k], wl[k * 96 + l], acc);
    m2[(size_t)b * 18432 + d * 96 + l] = acc;
}

// ---------------------------------------------------------------------------
// k4: out[r][l] = [x_row | ext_row(from VT bf16)] . M2[b][:,l] + bl[l]
// ---------------------------------------------------------------------------
__global__ __launch_bounds__(96) void k4_simple(
    const float* __restrict__ x, const unsigned short* __restrict__ vt,
    const float* __restrict__ m2, const float* __restrict__ bl,
    float* __restrict__ out)
{
    __shared__ float sx[128];
    __shared__ float sxe[64];
    const int r = blockIdx.x;
    const int b = r >> 11;
    const int c = r & 2047;
    const int t = threadIdx.x;
    for (int i = t; i < 128; i += 96) sx[i] = x[(size_t)r * 128 + i];
    if (t < 64) sxe[t] = bf2f(vt[(size_t)(b * 192 + 128 + t) * 2048 + c]);
    __syncthreads();
    const float* mb = m2 + (size_t)b * 18432;
    float a = bl[t];
    for (int k = 0; k < 128; ++k) a = fmaf(sx[k], mb[k * 96 + t], a);
    for (int k = 0; k < 64; ++k) a = fmaf(sxe[k], mb[(128 + k) * 96 + t], a);
    out[(size_t)r * 96 + t] = a;
}

// ---------------------------------------------------------------------------
extern "C" void kernel_launch(void* const* d_in, const int* in_sizes, int n_in,
                              void* d_out, int out_size, void* d_ws, size_t ws_size,
                              hipStream_t stream) {
    const float* x      = (const float*)d_in[0];
    const float* id_emb = (const float*)d_in[1];
    const float* w1     = (const float*)d_in[2];
    const float* b1     = (const float*)d_in[3];
    const float* w2     = (const float*)d_in[4];
    const float* b2     = (const float*)d_in[5];
    const float* ce     = (const float*)d_in[6];
    const float* wic    = (const float*)d_in[7];
    const float* bic    = (const float*)d_in[8];
    const float* wg     = (const float*)d_in[9];
    const float* bg     = (const float*)d_in[10];
    const float* cw     = (const float*)d_in[11];
    const float* wl     = (const float*)d_in[12];
    const float* bl     = (const float*)d_in[13];
    float* out = (float*)d_out;

    float* ws = (float*)d_ws;
    unsigned short* vt = (unsigned short*)ws;    // 3,145,728 float-equiv
    float* ge   = ws + 3145728;                  // 1,048,576
    float* wraw = ws + 4194304;                  //   589,824
    float* m2   = ws + 4784128;                  //   294,912
    float* sumv = ws + 5079040;                  //     3,072
    // total 5,082,112 floats = 20.3 MB

    hipMemsetAsync(wraw, 0, 589824 * sizeof(float), stream);
    hipLaunchKernelGGL(k0_transpose_x, dim3(32, 16), dim3(256), 0, stream, x, vt);
    hipLaunchKernelGGL(k1_simple, dim3(32768), dim3(128), 0, stream,
                       x, id_emb, w1, b1, w2, b2, ce, wic, bic, wg, bg, vt, ge);
    hipLaunchKernelGGL(k1b_sumv, dim3(192, 16), dim3(256), 0, stream, vt, sumv);
    hipLaunchKernelGGL(k2_fused, dim3(32, 16), dim3(256), 0, stream,
                       ge, vt, cw, sumv, wraw);
    hipLaunchKernelGGL(k3a_tanh, dim3(2304), dim3(256), 0, stream, wraw);
    hipLaunchKernelGGL(k3b_m2, dim3(96, 16), dim3(192), 0, stream,
                       wraw, wl, m2);
    hipLaunchKernelGGL(k4_simple, dim3(32768), dim3(96), 0, stream,
                       x, vt, m2, bl, out);
}

// Round 10
// 1268.088 us; speedup vs baseline: 1.5171x; 1.0126x over previous
//
#include <hip/hip_runtime.h>
#include <hip/hip_bf16.h>

// B=16, C=2048, T=128, ID=32, NC=16, CD=32, GD=32, OUT=96, GIN=192
// ws (floats): vt(bf16) @0 (3,145,728) | geb16(bf16) @3145728 (524,288) |
// wraw @3670016 (589,824) | m2 @4259840 (294,912) | sumv @4554752 (3,072)
//  => 18.2 MB total.
//
// ADJACENCY SEMANTICS: weight(m) = 0 if m==o; exp(s) if s>0; 1 if s<=0.
// Decomposition: d = weight-1 (d=-1 diag, exp(s)-1 if s>0, else 0).
// agg_unnorm = sumV + MFMA(d,V);  l = 2048 + sum(d).
// Round-10: S phase ALSO on MFMA (ge in bf16) — kills the 128 latency-bound
// ds_read_b128/wave/tile that made rounds 7-9 stall-bound (VALUBusy 9%).

typedef __attribute__((ext_vector_type(8))) short short8;
typedef __attribute__((ext_vector_type(16))) float f32x16;

__device__ __forceinline__ unsigned short f2bf(float f) {
    __hip_bfloat16 h = __float2bfloat16(f);
    return *reinterpret_cast<unsigned short*>(&h);
}
__device__ __forceinline__ float bf2f(unsigned short u) {
    __hip_bfloat16 h = *reinterpret_cast<__hip_bfloat16*>(&u);
    return __bfloat162float(h);
}

// ---------------------------------------------------------------------------
// k0: transpose x (fp32 [b][m][128]) -> VT bf16 [b][ch][m] for ch 0..127.
// ---------------------------------------------------------------------------
__global__ __launch_bounds__(256) void k0_transpose_x(
    const float* __restrict__ x, unsigned short* __restrict__ vt)
{
    __shared__ float sT[64 * 133];
    const int t = threadIdx.x;
    const int m0 = blockIdx.x * 64;
    const int b = blockIdx.y;
    const float* xb = x + (size_t)b * 2048 * 128;
    #pragma unroll
    for (int kk = 0; kk < 8; ++kk) {
        int i = t + kk * 256;
        int mm = i >> 5, q4 = i & 31;
        float4 v = ((const float4*)(xb + (size_t)(m0 + mm) * 128))[q4];
        float* d = sT + mm * 133 + q4 * 4;
        d[0] = v.x; d[1] = v.y; d[2] = v.z; d[3] = v.w;
    }
    __syncthreads();
    const int mp = t & 31;
    const int ch0 = t >> 5;
    #pragma unroll
    for (int pass = 0; pass < 16; ++pass) {
        int ch = ch0 + pass * 8;
        unsigned int u0 = f2bf(sT[(2 * mp) * 133 + ch]);
        unsigned int u1 = f2bf(sT[(2 * mp + 1) * 133 + ch]);
        *((unsigned int*)(vt + (size_t)(b * 192 + ch) * 2048 + m0) + mp) =
            u0 | (u1 << 16);
    }
}

// ---------------------------------------------------------------------------
// k1: per-row features. One block (128 thr) per row r. Writes VT channels
// 128..191 (bf16) and ge row as bf16 (for the MFMA S phase).
// ---------------------------------------------------------------------------
__global__ __launch_bounds__(128) void k1_simple(
    const float* __restrict__ x, const float* __restrict__ id_emb,
    const float* __restrict__ w1, const float* __restrict__ b1,
    const float* __restrict__ w2, const float* __restrict__ b2,
    const float* __restrict__ ce, const float* __restrict__ wic,
    const float* __restrict__ bic, const float* __restrict__ wg,
    const float* __restrict__ bg, unsigned short* __restrict__ vt,
    unsigned short* __restrict__ geb16)
{
    __shared__ float sx[128];
    __shared__ float sh[64];
    __shared__ float sid[32];
    __shared__ float sic[32];
    __shared__ float sp[16];
    __shared__ float scl[32];

    const int r = blockIdx.x;
    const int b = r >> 11;
    const int c = r & 2047;
    const int t = threadIdx.x;

    sx[t] = x[(size_t)r * 128 + t];
    __syncthreads();

    if (t < 64) {
        float a = b1[t];
        for (int k = 0; k < 128; ++k) a = fmaf(sx[k], w1[k * 64 + t], a);
        sh[t] = fmaxf(a, 0.f);
    }
    __syncthreads();

    if (t < 32) {
        float a = b2[t];
        for (int k = 0; k < 64; ++k) a = fmaf(sh[k], w2[k * 32 + t], a);
        float ide = id_emb[c * 32 + t] + a;
        sid[t] = ide;
        vt[(size_t)(b * 192 + 128 + t) * 2048 + c] = f2bf(ide);
    }
    __syncthreads();

    if (t < 32) {
        float a = bic[t];
        for (int k = 0; k < 32; ++k) a = fmaf(sid[k], wic[k * 32 + t], a);
        sic[t] = a;
    }
    __syncthreads();

    if (t < 16) {
        float a = 0.f;
        for (int k = 0; k < 32; ++k) a = fmaf(sic[k], ce[t * 32 + k], a);
        sp[t] = a;
    }
    __syncthreads();

    if (t == 0) {
        float mx = sp[0];
        for (int n = 1; n < 16; ++n) mx = fmaxf(mx, sp[n]);
        float ss = 0.f;
        for (int n = 0; n < 16; ++n) { float e = __expf(sp[n] - mx); sp[n] = e; ss += e; }
        float inv = 1.f / ss;
        for (int n = 0; n < 16; ++n) sp[n] *= inv;
    }
    __syncthreads();

    if (t < 32) {
        float a = 0.f;
        for (int n = 0; n < 16; ++n) a = fmaf(sp[n], ce[n * 32 + t], a);
        scl[t] = a;
        vt[(size_t)(b * 192 + 160 + t) * 2048 + c] = f2bf(a);
    }
    __syncthreads();

    if (t < 32) {
        float a = bg[t];
        for (int k = 0; k < 32; ++k) a = fmaf(sid[k], wg[k * 32 + t], a);
        for (int k = 0; k < 32; ++k) a = fmaf(scl[k], wg[(32 + k) * 32 + t], a);
        geb16[(size_t)r * 32 + t] = f2bf(a);
    }
}

// ---------------------------------------------------------------------------
// k1b: sumV[b][ch] = sum_m VT[b][ch][m] (fp32 accumulate of bf16).
// ---------------------------------------------------------------------------
__global__ __launch_bounds__(256) void k1b_sumv(
    const unsigned short* __restrict__ vt, float* __restrict__ sumv)
{
    __shared__ float red[256];
    const int ch = blockIdx.x, b = blockIdx.y, t = threadIdx.x;
    const unsigned short* row = vt + (size_t)(b * 192 + ch) * 2048;
    float a = 0.f;
    #pragma unroll
    for (int j = 0; j < 8; ++j) a += bf2f(row[t * 8 + j]);
    red[t] = a; __syncthreads();
    for (int off = 128; off > 0; off >>= 1) {
        if (t < off) red[t] += red[t + off];
        __syncthreads();
    }
    if (t == 0) sumv[b * 192 + ch] = red[0];
}

// ---------------------------------------------------------------------------
// k2: all-MFMA core. Per tile: stage ge-tile + V-tile (bf16) -> S via
// 32x32x16 MFMA (2/wave) -> d=exp(s)-1 on 16 C-frag values/lane -> dw bf16
// -> PV via MFMA (12/wave) -> epilogue (sumV + D)/l -> cw contraction ->
// atomicAdd wraw. Wave w: S o-sub (w&1)*32 / m-sub (w>>1)*32;
// PV o-sub (w&1)*32 / ch-third base (w>>1)*96.
// ---------------------------------------------------------------------------
__global__ __launch_bounds__(256) void k2_fused(
    const unsigned short* __restrict__ geb16,
    const unsigned short* __restrict__ vt,
    const float* __restrict__ cw, const float* __restrict__ sumv,
    float* __restrict__ wraw)
{
    __shared__ float s_agg[64 * 193];   // 12352 f; K-loop arrays alias inside
    __shared__ float sinv[64];
    __shared__ float s_sum[192];
    unsigned short* sGeO = (unsigned short*)(s_agg);          // [64][40] bf16
    unsigned short* sGe  = (unsigned short*)(s_agg + 1280);   // [64][40] bf16
    unsigned short* sVt  = (unsigned short*)(s_agg + 2560);   // [192][72] bf16
    unsigned short* dw   = (unsigned short*)(s_agg + 9472);   // [64][72] bf16
    float* lpbuf = s_agg;                                     // [64][68] post-loop

    const int t = threadIdx.x;
    const int b = blockIdx.y;
    const int o0 = blockIdx.x * 64;
    const unsigned short* geb = geb16 + (size_t)b * 2048 * 32;
    const unsigned short* vtb = vt + (size_t)b * 192 * 2048;

    const int lane = t & 63;
    const int mg = t >> 6;
    const int col = lane & 31;
    const int grp = lane >> 5;
    const int os = (mg & 1) * 32;       // S phase o-sub
    const int ms = (mg >> 1) * 32;      // S phase m-sub
    const int orow0 = (mg & 1) * 32;    // PV o-sub
    const int dbase = (mg >> 1) * 96;   // PV ch-third

    if (t < 192) s_sum[t] = sumv[b * 192 + t];

    // stage own ge rows (o0..o0+63) once
    {
        int row = t >> 2, c8 = t & 3;
        short8 v = *(const short8*)(geb + (size_t)(o0 + row) * 32 + c8 * 8);
        *(short8*)(sGeO + row * 40 + c8 * 8) = v;
    }

    f32x16 acc0, acc1, acc2;
    #pragma unroll
    for (int i = 0; i < 16; ++i) { acc0[i] = 0.f; acc1[i] = 0.f; acc2[i] = 0.f; }
    float lpA[16];
    #pragma unroll
    for (int i = 0; i < 16; ++i) lpA[i] = 0.f;

    for (int m0 = 0; m0 < 2048; m0 += 64) {
        // stage ge m-tile (64x32 bf16): 1 short8/thread
        {
            int row = t >> 2, c8 = t & 3;
            short8 v = *(const short8*)(geb + (size_t)(m0 + row) * 32 + c8 * 8);
            *(short8*)(sGe + row * 40 + c8 * 8) = v;
        }
        // stage sVt (192ch x 64m bf16): 6 short8/thread
        #pragma unroll
        for (int kk = 0; kk < 6; ++kk) {
            int i = t + kk * 256;
            int ch = i >> 3, m8 = i & 7;
            short8 v = *(const short8*)(vtb + (size_t)ch * 2048 + m0 + m8 * 8);
            *(short8*)(sVt + ch * 72 + m8 * 8) = v;
        }
        __syncthreads();

        // S phase: 2 MFMAs (K=32) -> s values in C-frag
        f32x16 sacc;
        #pragma unroll
        for (int i = 0; i < 16; ++i) sacc[i] = 0.f;
        #pragma unroll
        for (int ks = 0; ks < 2; ++ks) {
            short8 A  = *(const short8*)(sGeO + (os + col) * 40 + ks * 16 + grp * 8);
            short8 Bf = *(const short8*)(sGe + (ms + col) * 40 + ks * 16 + grp * 8);
            sacc = __builtin_amdgcn_mfma_f32_32x32x16_bf16(A, Bf, sacc, 0, 0, 0);
        }
        // d = weight-1 on 16 values/lane; write dw bf16; accumulate lp per row
        {
            const int m_local = ms + col;
            const int gm = m0 + m_local;
            #pragma unroll
            for (int r = 0; r < 16; ++r) {
                int o_local = os + (r & 3) + 8 * (r >> 2) + 4 * grp;
                float s = sacc[r];
                float d = (gm == o0 + o_local) ? -1.f
                        : ((s > 0.f) ? (__expf(s) - 1.f) : 0.f);
                lpA[r] += d;
                dw[o_local * 72 + m_local] = f2bf(d);
            }
        }
        __syncthreads();

        // PV phase: 12 MFMAs
        #pragma unroll
        for (int ks = 0; ks < 4; ++ks) {
            short8 A  = *(const short8*)(dw + (orow0 + col) * 72 + ks * 16 + grp * 8);
            short8 B0 = *(const short8*)(sVt + (dbase + col) * 72 + ks * 16 + grp * 8);
            short8 B1 = *(const short8*)(sVt + (dbase + 32 + col) * 72 + ks * 16 + grp * 8);
            short8 B2 = *(const short8*)(sVt + (dbase + 64 + col) * 72 + ks * 16 + grp * 8);
            acc0 = __builtin_amdgcn_mfma_f32_32x32x16_bf16(A, B0, acc0, 0, 0, 0);
            acc1 = __builtin_amdgcn_mfma_f32_32x32x16_bf16(A, B1, acc1, 0, 0, 0);
            acc2 = __builtin_amdgcn_mfma_f32_32x32x16_bf16(A, B2, acc2, 0, 0, 0);
        }
        __syncthreads();
    }

    // lp reduction: lpbuf[(widx*32+col)][ol] (stride 68), then 64-thread sum
    {
        const int widx = mg >> 1;
        #pragma unroll
        for (int r = 0; r < 16; ++r) {
            int ol = os + (r & 3) + 8 * (r >> 2) + 4 * grp;
            lpbuf[(widx * 32 + col) * 68 + ol] = lpA[r];
        }
    }
    __syncthreads();
    if (t < 64) {
        float l = 2048.f;
        for (int i = 0; i < 64; ++i) l += lpbuf[i * 68 + t];
        sinv[t] = 1.f / l;
    }
    __syncthreads();

    // epilogue: agg = (sumV + D) / l -> s_agg (overwrites K-loop arrays)
    {
        f32x16 av[3] = {acc0, acc1, acc2};
        #pragma unroll
        for (int n = 0; n < 3; ++n) {
            int chn = dbase + n * 32 + col;
            float sv = s_sum[chn];
            #pragma unroll
            for (int r = 0; r < 16; ++r) {
                int ol = orow0 + (r & 3) + 8 * (r >> 2) + 4 * grp;
                s_agg[ol * 193 + chn] = (sv + av[n][r]) * sinv[ol];
            }
        }
    }
    __syncthreads();

    // contribution[d][l] = sum_oo agg[oo][d]*cw[o0+oo][l]; 12x12 per thread
    {
        const int dgi = t >> 4, lg = t & 15;
        const int d0t = dgi * 12, l0t = lg * 12;
        float acc2r[12][12];
        #pragma unroll
        for (int i = 0; i < 12; ++i)
            #pragma unroll
            for (int j = 0; j < 12; ++j) acc2r[i][j] = 0.f;
        for (int oo = 0; oo < 64; ++oo) {
            float a[12], cc[12];
            const float* ar = s_agg + oo * 193 + d0t;
            const float* cr = cw + (size_t)(o0 + oo) * 192 + l0t;
            #pragma unroll
            for (int i = 0; i < 12; ++i) a[i] = ar[i];
            #pragma unroll
            for (int j = 0; j < 12; ++j) cc[j] = cr[j];
            #pragma unroll
            for (int i = 0; i < 12; ++i)
                #pragma unroll
                for (int j = 0; j < 12; ++j)
                    acc2r[i][j] = fmaf(a[i], cc[j], acc2r[i][j]);
        }
        float* wb = wraw + (size_t)b * 36864;
        #pragma unroll
        for (int i = 0; i < 12; ++i)
            #pragma unroll
            for (int j = 0; j < 12; ++j)
                atomicAdd(&wb[(d0t + i) * 192 + l0t + j], acc2r[i][j]);
    }
}

// ---------------------------------------------------------------------------
__global__ __launch_bounds__(256) void k3a_tanh(float* __restrict__ wraw)
{
    int i = blockIdx.x * 256 + threadIdx.x;
    wraw[i] = tanhf(wraw[i]);
}

// ---------------------------------------------------------------------------
__global__ __launch_bounds__(192) void k3b_m2(
    const float* __restrict__ wmat, const float* __restrict__ wl,
    float* __restrict__ m2)
{
    const int t = threadIdx.x;
    const int b = blockIdx.y;
    const int d = blockIdx.x * 2 + (t / 96);
    const int l = t % 96;
    const float* wrow = wmat + (size_t)b * 36864 + d * 192;
    float acc = wl[d * 96 + l];
    for (int k = 0; k < 192; ++k)
        acc = fmaf(wrow[k], wl[k * 96 + l], acc);
    m2[(size_t)b * 18432 + d * 96 + l] = acc;
}

// ---------------------------------------------------------------------------
// k4: out[r][l] = [x_row | ext_row(from VT bf16)] . M2[b][:,l] + bl[l]
// ---------------------------------------------------------------------------
__global__ __launch_bounds__(96) void k4_simple(
    const float* __restrict__ x, const unsigned short* __restrict__ vt,
    const float* __restrict__ m2, const float* __restrict__ bl,
    float* __restrict__ out)
{
    __shared__ float sx[128];
    __shared__ float sxe[64];
    const int r = blockIdx.x;
    const int b = r >> 11;
    const int c = r & 2047;
    const int t = threadIdx.x;
    for (int i = t; i < 128; i += 96) sx[i] = x[(size_t)r * 128 + i];
    if (t < 64) sxe[t] = bf2f(vt[(size_t)(b * 192 + 128 + t) * 2048 + c]);
    __syncthreads();
    const float* mb = m2 + (size_t)b * 18432;
    float a = bl[t];
    for (int k = 0; k < 128; ++k) a = fmaf(sx[k], mb[k * 96 + t], a);
    for (int k = 0; k < 64; ++k) a = fmaf(sxe[k], mb[(128 + k) * 96 + t], a);
    out[(size_t)r * 96 + t] = a;
}

// ---------------------------------------------------------------------------
extern "C" void kernel_launch(void* const* d_in, const int* in_sizes, int n_in,
                              void* d_out, int out_size, void* d_ws, size_t ws_size,
                              hipStream_t stream) {
    const float* x      = (const float*)d_in[0];
    const float* id_emb = (const float*)d_in[1];
    const float* w1     = (const float*)d_in[2];
    const float* b1     = (const float*)d_in[3];
    const float* w2     = (const float*)d_in[4];
    const float* b2     = (const float*)d_in[5];
    const float* ce     = (const float*)d_in[6];
    const float* wic    = (const float*)d_in[7];
    const float* bic    = (const float*)d_in[8];
    const float* wg     = (const float*)d_in[9];
    const float* bg     = (const float*)d_in[10];
    const float* cw     = (const float*)d_in[11];
    const float* wl     = (const float*)d_in[12];
    const float* bl     = (const float*)d_in[13];
    float* out = (float*)d_out;

    float* ws = (float*)d_ws;
    unsigned short* vt    = (unsigned short*)ws;            // 3,145,728 f-equiv
    unsigned short* geb16 = (unsigned short*)(ws + 3145728); //  524,288 f-equiv
    float* wraw = ws + 3670016;                              //  589,824
    float* m2   = ws + 4259840;                              //  294,912
    float* sumv = ws + 4554752;                              //    3,072
    // total 4,557,824 floats = 18.2 MB

    hipMemsetAsync(wraw, 0, 589824 * sizeof(float), stream);
    hipLaunchKernelGGL(k0_transpose_x, dim3(32, 16), dim3(256), 0, stream, x, vt);
    hipLaunchKernelGGL(k1_simple, dim3(32768), dim3(128), 0, stream,
                       x, id_emb, w1, b1, w2, b2, ce, wic, bic, wg, bg, vt, geb16);
    hipLaunchKernelGGL(k1b_sumv, dim3(192, 16), dim3(256), 0, stream, vt, sumv);
    hipLaunchKernelGGL(k2_fused, dim3(32, 16), dim3(256), 0, stream,
                       geb16, vt, cw, sumv, wraw);
    hipLaunchKernelGGL(k3a_tanh, dim3(2304), dim3(256), 0, stream, wraw);
    hipLaunchKernelGGL(k3b_m2, dim3(96, 16), dim3(192), 0, stream,
                       wraw, wl, m2);
    hipLaunchKernelGGL(k4_simple, dim3(32768), dim3(96), 0, stream,
                       x, vt, m2, bl, out);
}

// Round 12
// 529.536 us; speedup vs baseline: 3.6329x; 2.3947x over previous
//
#include <hip/hip_runtime.h>
#include <hip/hip_bf16.h>

// B=16, C=2048, T=128, ID=32, NC=16, CD=32, GD=32, OUT=96, GIN=192
// ws (floats): vt(bf16) @0 (3,145,728) | geb16(bf16) @3145728 (524,288) |
// aggb(bf16) @3670016 (3,145,728) | wraw @6815744 (589,824) |
// m2 @7405568 (294,912) | sumv @7700480 (3,072) => 30.8 MB total.
//
// ADJACENCY SEMANTICS: weight(m) = 0 if m==o; exp(s) if s>0; 1 if s<=0.
// Decomposition: d = weight-1 (d=-1 diag, exp(s)-1 if s>0, else 0).
// agg_unnorm = sumV + MFMA(d,V);  l = 2048 + sum(d).
// Round-12: identical to round 11 EXCEPT s_buf sized 9472 floats (round 11
// sized it 4352 for lpbuf only; sVt @2560+6912 overran it -> LDS corruption).

typedef __attribute__((ext_vector_type(8))) short short8;
typedef __attribute__((ext_vector_type(16))) float f32x16;

__device__ __forceinline__ unsigned short f2bf(float f) {
    __hip_bfloat16 h = __float2bfloat16(f);
    return *reinterpret_cast<unsigned short*>(&h);
}
__device__ __forceinline__ float bf2f(unsigned short u) {
    __hip_bfloat16 h = *reinterpret_cast<__hip_bfloat16*>(&u);
    return __bfloat162float(h);
}

// ---------------------------------------------------------------------------
// k0: transpose x (fp32 [b][m][128]) -> VT bf16 [b][ch][m] for ch 0..127.
// ---------------------------------------------------------------------------
__global__ __launch_bounds__(256) void k0_transpose_x(
    const float* __restrict__ x, unsigned short* __restrict__ vt)
{
    __shared__ float sT[64 * 133];
    const int t = threadIdx.x;
    const int m0 = blockIdx.x * 64;
    const int b = blockIdx.y;
    const float* xb = x + (size_t)b * 2048 * 128;
    #pragma unroll
    for (int kk = 0; kk < 8; ++kk) {
        int i = t + kk * 256;
        int mm = i >> 5, q4 = i & 31;
        float4 v = ((const float4*)(xb + (size_t)(m0 + mm) * 128))[q4];
        float* d = sT + mm * 133 + q4 * 4;
        d[0] = v.x; d[1] = v.y; d[2] = v.z; d[3] = v.w;
    }
    __syncthreads();
    const int mp = t & 31;
    const int ch0 = t >> 5;
    #pragma unroll
    for (int pass = 0; pass < 16; ++pass) {
        int ch = ch0 + pass * 8;
        unsigned int u0 = f2bf(sT[(2 * mp) * 133 + ch]);
        unsigned int u1 = f2bf(sT[(2 * mp + 1) * 133 + ch]);
        *((unsigned int*)(vt + (size_t)(b * 192 + ch) * 2048 + m0) + mp) =
            u0 | (u1 << 16);
    }
}

// ---------------------------------------------------------------------------
// k1: per-row features. One block (128 thr) per row r. Writes VT channels
// 128..191 (bf16) and ge row as bf16 (for the MFMA S phase).
// ---------------------------------------------------------------------------
__global__ __launch_bounds__(128) void k1_simple(
    const float* __restrict__ x, const float* __restrict__ id_emb,
    const float* __restrict__ w1, const float* __restrict__ b1,
    const float* __restrict__ w2, const float* __restrict__ b2,
    const float* __restrict__ ce, const float* __restrict__ wic,
    const float* __restrict__ bic, const float* __restrict__ wg,
    const float* __restrict__ bg, unsigned short* __restrict__ vt,
    unsigned short* __restrict__ geb16)
{
    __shared__ float sx[128];
    __shared__ float sh[64];
    __shared__ float sid[32];
    __shared__ float sic[32];
    __shared__ float sp[16];
    __shared__ float scl[32];

    const int r = blockIdx.x;
    const int b = r >> 11;
    const int c = r & 2047;
    const int t = threadIdx.x;

    sx[t] = x[(size_t)r * 128 + t];
    __syncthreads();

    if (t < 64) {
        float a = b1[t];
        for (int k = 0; k < 128; ++k) a = fmaf(sx[k], w1[k * 64 + t], a);
        sh[t] = fmaxf(a, 0.f);
    }
    __syncthreads();

    if (t < 32) {
        float a = b2[t];
        for (int k = 0; k < 64; ++k) a = fmaf(sh[k], w2[k * 32 + t], a);
        float ide = id_emb[c * 32 + t] + a;
        sid[t] = ide;
        vt[(size_t)(b * 192 + 128 + t) * 2048 + c] = f2bf(ide);
    }
    __syncthreads();

    if (t < 32) {
        float a = bic[t];
        for (int k = 0; k < 32; ++k) a = fmaf(sid[k], wic[k * 32 + t], a);
        sic[t] = a;
    }
    __syncthreads();

    if (t < 16) {
        float a = 0.f;
        for (int k = 0; k < 32; ++k) a = fmaf(sic[k], ce[t * 32 + k], a);
        sp[t] = a;
    }
    __syncthreads();

    if (t == 0) {
        float mx = sp[0];
        for (int n = 1; n < 16; ++n) mx = fmaxf(mx, sp[n]);
        float ss = 0.f;
        for (int n = 0; n < 16; ++n) { float e = __expf(sp[n] - mx); sp[n] = e; ss += e; }
        float inv = 1.f / ss;
        for (int n = 0; n < 16; ++n) sp[n] *= inv;
    }
    __syncthreads();

    if (t < 32) {
        float a = 0.f;
        for (int n = 0; n < 16; ++n) a = fmaf(sp[n], ce[n * 32 + t], a);
        scl[t] = a;
        vt[(size_t)(b * 192 + 160 + t) * 2048 + c] = f2bf(a);
    }
    __syncthreads();

    if (t < 32) {
        float a = bg[t];
        for (int k = 0; k < 32; ++k) a = fmaf(sid[k], wg[k * 32 + t], a);
        for (int k = 0; k < 32; ++k) a = fmaf(scl[k], wg[(32 + k) * 32 + t], a);
        geb16[(size_t)r * 32 + t] = f2bf(a);
    }
}

// ---------------------------------------------------------------------------
// k1b: sumV[b][ch] = sum_m VT[b][ch][m] (fp32 accumulate of bf16).
// ---------------------------------------------------------------------------
__global__ __launch_bounds__(256) void k1b_sumv(
    const unsigned short* __restrict__ vt, float* __restrict__ sumv)
{
    __shared__ float red[256];
    const int ch = blockIdx.x, b = blockIdx.y, t = threadIdx.x;
    const unsigned short* row = vt + (size_t)(b * 192 + ch) * 2048;
    float a = 0.f;
    #pragma unroll
    for (int j = 0; j < 8; ++j) a += bf2f(row[t * 8 + j]);
    red[t] = a; __syncthreads();
    for (int off = 128; off > 0; off >>= 1) {
        if (t < off) red[t] += red[t + off];
        __syncthreads();
    }
    if (t == 0) sumv[b * 192 + ch] = red[0];
}

// ---------------------------------------------------------------------------
// k2: all-MFMA core (K-loop identical to round 10). Epilogue writes the
// normalized agg tile to global aggb (bf16, plain stores — NO atomics).
// s_buf = 9472 floats: K-loop layout sGeO(1280)|sGe(1280)|sVt(6912);
// post-loop lpbuf[64][68]=4352 aliases the front. dw is separate.
// ---------------------------------------------------------------------------
__global__ __launch_bounds__(256) void k2_fused(
    const unsigned short* __restrict__ geb16,
    const unsigned short* __restrict__ vt,
    const float* __restrict__ sumv,
    unsigned short* __restrict__ aggb)
{
    __shared__ float s_buf[9472];
    __shared__ float sinv[64];
    __shared__ float s_sum[192];
    __shared__ unsigned short dw[64 * 72];
    unsigned short* sGeO = (unsigned short*)(s_buf);          // [64][40] bf16
    unsigned short* sGe  = (unsigned short*)(s_buf + 1280);   // [64][40] bf16
    unsigned short* sVt  = (unsigned short*)(s_buf + 2560);   // [192][72] bf16
    float* lpbuf = s_buf;                                     // [64][68] post-loop

    const int t = threadIdx.x;
    const int b = blockIdx.y;
    const int o0 = blockIdx.x * 64;
    const unsigned short* geb = geb16 + (size_t)b * 2048 * 32;
    const unsigned short* vtb = vt + (size_t)b * 192 * 2048;

    const int lane = t & 63;
    const int mg = t >> 6;
    const int col = lane & 31;
    const int grp = lane >> 5;
    const int os = (mg & 1) * 32;       // S phase o-sub
    const int ms = (mg >> 1) * 32;      // S phase m-sub
    const int orow0 = (mg & 1) * 32;    // PV o-sub
    const int dbase = (mg >> 1) * 96;   // PV ch-third

    if (t < 192) s_sum[t] = sumv[b * 192 + t];

    // stage own ge rows (o0..o0+63) once
    {
        int row = t >> 2, c8 = t & 3;
        short8 v = *(const short8*)(geb + (size_t)(o0 + row) * 32 + c8 * 8);
        *(short8*)(sGeO + row * 40 + c8 * 8) = v;
    }

    f32x16 acc0, acc1, acc2;
    #pragma unroll
    for (int i = 0; i < 16; ++i) { acc0[i] = 0.f; acc1[i] = 0.f; acc2[i] = 0.f; }
    float lpA[16];
    #pragma unroll
    for (int i = 0; i < 16; ++i) lpA[i] = 0.f;

    for (int m0 = 0; m0 < 2048; m0 += 64) {
        // stage ge m-tile (64x32 bf16): 1 short8/thread
        {
            int row = t >> 2, c8 = t & 3;
            short8 v = *(const short8*)(geb + (size_t)(m0 + row) * 32 + c8 * 8);
            *(short8*)(sGe + row * 40 + c8 * 8) = v;
        }
        // stage sVt (192ch x 64m bf16): 6 short8/thread
        #pragma unroll
        for (int kk = 0; kk < 6; ++kk) {
            int i = t + kk * 256;
            int ch = i >> 3, m8 = i & 7;
            short8 v = *(const short8*)(vtb + (size_t)ch * 2048 + m0 + m8 * 8);
            *(short8*)(sVt + ch * 72 + m8 * 8) = v;
        }
        __syncthreads();

        // S phase: 2 MFMAs (K=32) -> s values in C-frag
        f32x16 sacc;
        #pragma unroll
        for (int i = 0; i < 16; ++i) sacc[i] = 0.f;
        #pragma unroll
        for (int ks = 0; ks < 2; ++ks) {
            short8 A  = *(const short8*)(sGeO + (os + col) * 40 + ks * 16 + grp * 8);
            short8 Bf = *(const short8*)(sGe + (ms + col) * 40 + ks * 16 + grp * 8);
            sacc = __builtin_amdgcn_mfma_f32_32x32x16_bf16(A, Bf, sacc, 0, 0, 0);
        }
        // d = weight-1 on 16 values/lane; write dw bf16; accumulate lp per row
        {
            const int m_local = ms + col;
            const int gm = m0 + m_local;
            #pragma unroll
            for (int r = 0; r < 16; ++r) {
                int o_local = os + (r & 3) + 8 * (r >> 2) + 4 * grp;
                float s = sacc[r];
                float d = (gm == o0 + o_local) ? -1.f
                        : ((s > 0.f) ? (__expf(s) - 1.f) : 0.f);
                lpA[r] += d;
                dw[o_local * 72 + m_local] = f2bf(d);
            }
        }
        __syncthreads();

        // PV phase: 12 MFMAs
        #pragma unroll
        for (int ks = 0; ks < 4; ++ks) {
            short8 A  = *(const short8*)(dw + (orow0 + col) * 72 + ks * 16 + grp * 8);
            short8 B0 = *(const short8*)(sVt + (dbase + col) * 72 + ks * 16 + grp * 8);
            short8 B1 = *(const short8*)(sVt + (dbase + 32 + col) * 72 + ks * 16 + grp * 8);
            short8 B2 = *(const short8*)(sVt + (dbase + 64 + col) * 72 + ks * 16 + grp * 8);
            acc0 = __builtin_amdgcn_mfma_f32_32x32x16_bf16(A, B0, acc0, 0, 0, 0);
            acc1 = __builtin_amdgcn_mfma_f32_32x32x16_bf16(A, B1, acc1, 0, 0, 0);
            acc2 = __builtin_amdgcn_mfma_f32_32x32x16_bf16(A, B2, acc2, 0, 0, 0);
        }
        __syncthreads();
    }

    // lp reduction: lpbuf[(widx*32+col)][ol] (stride 68), then 64-thread sum
    {
        const int widx = mg >> 1;
        #pragma unroll
        for (int r = 0; r < 16; ++r) {
            int ol = os + (r & 3) + 8 * (r >> 2) + 4 * grp;
            lpbuf[(widx * 32 + col) * 68 + ol] = lpA[r];
        }
    }
    __syncthreads();
    if (t < 64) {
        float l = 2048.f;
        for (int i = 0; i < 64; ++i) l += lpbuf[i * 68 + t];
        sinv[t] = 1.f / l;
    }
    __syncthreads();

    // epilogue: agg = (sumV + D) / l -> global aggb (bf16, plain stores)
    {
        f32x16 av[3] = {acc0, acc1, acc2};
        unsigned short* ab = aggb + (size_t)b * 2048 * 192;
        #pragma unroll
        for (int n = 0; n < 3; ++n) {
            int chn = dbase + n * 32 + col;
            float sv = s_sum[chn];
            #pragma unroll
            for (int r = 0; r < 16; ++r) {
                int ol = orow0 + (r & 3) + 8 * (r >> 2) + 4 * grp;
                ab[(size_t)(o0 + ol) * 192 + chn] =
                    f2bf((sv + av[n][r]) * sinv[ol]);
            }
        }
    }
}

// ---------------------------------------------------------------------------
// k3_ctx: w[b][d][l] = tanh(sum_o agg[b][o][d] * cw[o][l]).
// 64x64 tiles, K=2048 in chunks of 64, 4x4 acc per thread. Full coverage.
// ---------------------------------------------------------------------------
__global__ __launch_bounds__(256) void k3_ctx(
    const unsigned short* __restrict__ aggb, const float* __restrict__ cw,
    float* __restrict__ wraw)
{
    __shared__ float sA[64 * 68];
    __shared__ float sW[64 * 68];
    const int t = threadIdx.x;
    const int b = blockIdx.z;
    const int d0 = blockIdx.x * 64;
    const int l0 = blockIdx.y * 64;
    const unsigned short* ab = aggb + (size_t)b * 2048 * 192;
    const int ti = t >> 4, tj = t & 15;
    float acc[4][4] = {{0.f}};

    for (int o0 = 0; o0 < 2048; o0 += 64) {
        for (int i = t; i < 4096; i += 256) {
            int oo = i >> 6, dd = i & 63;
            sA[oo * 68 + dd] = bf2f(ab[(size_t)(o0 + oo) * 192 + d0 + dd]);
            sW[oo * 68 + dd] = cw[(size_t)(o0 + oo) * 192 + l0 + dd];
        }
        __syncthreads();
        for (int o = 0; o < 64; ++o) {
            const float* ap = sA + o * 68 + ti * 4;
            const float* wp = sW + o * 68 + tj * 4;
            float a0 = ap[0], a1 = ap[1], a2 = ap[2], a3 = ap[3];
            float w0 = wp[0], w1v = wp[1], w2v = wp[2], w3 = wp[3];
            acc[0][0] = fmaf(a0, w0, acc[0][0]); acc[0][1] = fmaf(a0, w1v, acc[0][1]);
            acc[0][2] = fmaf(a0, w2v, acc[0][2]); acc[0][3] = fmaf(a0, w3, acc[0][3]);
            acc[1][0] = fmaf(a1, w0, acc[1][0]); acc[1][1] = fmaf(a1, w1v, acc[1][1]);
            acc[1][2] = fmaf(a1, w2v, acc[1][2]); acc[1][3] = fmaf(a1, w3, acc[1][3]);
            acc[2][0] = fmaf(a2, w0, acc[2][0]); acc[2][1] = fmaf(a2, w1v, acc[2][1]);
            acc[2][2] = fmaf(a2, w2v, acc[2][2]); acc[2][3] = fmaf(a2, w3, acc[2][3]);
            acc[3][0] = fmaf(a3, w0, acc[3][0]); acc[3][1] = fmaf(a3, w1v, acc[3][1]);
            acc[3][2] = fmaf(a3, w2v, acc[3][2]); acc[3][3] = fmaf(a3, w3, acc[3][3]);
        }
        __syncthreads();
    }
    float* wb = wraw + (size_t)b * 36864;
    #pragma unroll
    for (int i = 0; i < 4; ++i)
        #pragma unroll
        for (int j = 0; j < 4; ++j)
            wb[(d0 + ti * 4 + i) * 192 + l0 + tj * 4 + j] = tanhf(acc[i][j]);
}

// ---------------------------------------------------------------------------
__global__ __launch_bounds__(192) void k3b_m2(
    const float* __restrict__ wmat, const float* __restrict__ wl,
    float* __restrict__ m2)
{
    const int t = threadIdx.x;
    const int b = blockIdx.y;
    const int d = blockIdx.x * 2 + (t / 96);
    const int l = t % 96;
    const float* wrow = wmat + (size_t)b * 36864 + d * 192;
    float acc = wl[d * 96 + l];
    for (int k = 0; k < 192; ++k)
        acc = fmaf(wrow[k], wl[k * 96 + l], acc);
    m2[(size_t)b * 18432 + d * 96 + l] = acc;
}

// ---------------------------------------------------------------------------
// k4: out[r][l] = [x_row | ext_row(from VT bf16)] . M2[b][:,l] + bl[l]
// ---------------------------------------------------------------------------
__global__ __launch_bounds__(96) void k4_simple(
    const float* __restrict__ x, const unsigned short* __restrict__ vt,
    const float* __restrict__ m2, const float* __restrict__ bl,
    float* __restrict__ out)
{
    __shared__ float sx[128];
    __shared__ float sxe[64];
    const int r = blockIdx.x;
    const int b = r >> 11;
    const int c = r & 2047;
    const int t = threadIdx.x;
    for (int i = t; i < 128; i += 96) sx[i] = x[(size_t)r * 128 + i];
    if (t < 64) sxe[t] = bf2f(vt[(size_t)(b * 192 + 128 + t) * 2048 + c]);
    __syncthreads();
    const float* mb = m2 + (size_t)b * 18432;
    float a = bl[t];
    for (int k = 0; k < 128; ++k) a = fmaf(sx[k], mb[k * 96 + t], a);
    for (int k = 0; k < 64; ++k) a = fmaf(sxe[k], mb[(128 + k) * 96 + t], a);
    out[(size_t)r * 96 + t] = a;
}

// ---------------------------------------------------------------------------
extern "C" void kernel_launch(void* const* d_in, const int* in_sizes, int n_in,
                              void* d_out, int out_size, void* d_ws, size_t ws_size,
                              hipStream_t stream) {
    const float* x      = (const float*)d_in[0];
    const float* id_emb = (const float*)d_in[1];
    const float* w1     = (const float*)d_in[2];
    const float* b1     = (const float*)d_in[3];
    const float* w2     = (const float*)d_in[4];
    const float* b2     = (const float*)d_in[5];
    const float* ce     = (const float*)d_in[6];
    const float* wic    = (const float*)d_in[7];
    const float* bic    = (const float*)d_in[8];
    const float* wg     = (const float*)d_in[9];
    const float* bg     = (const float*)d_in[10];
    const float* cw     = (const float*)d_in[11];
    const float* wl     = (const float*)d_in[12];
    const float* bl     = (const float*)d_in[13];
    float* out = (float*)d_out;

    float* ws = (float*)d_ws;
    unsigned short* vt    = (unsigned short*)ws;             // 3,145,728 f-eq
    unsigned short* geb16 = (unsigned short*)(ws + 3145728); //   524,288 f-eq
    unsigned short* aggb  = (unsigned short*)(ws + 3670016); // 3,145,728 f-eq
    float* wraw = ws + 6815744;                              //   589,824
    float* m2   = ws + 7405568;                              //   294,912
    float* sumv = ws + 7700480;                              //     3,072
    // total 7,703,552 floats = 30.8 MB

    hipLaunchKernelGGL(k0_transpose_x, dim3(32, 16), dim3(256), 0, stream, x, vt);
    hipLaunchKernelGGL(k1_simple, dim3(32768), dim3(128), 0, stream,
                       x, id_emb, w1, b1, w2, b2, ce, wic, bic, wg, bg, vt, geb16);
    hipLaunchKernelGGL(k1b_sumv, dim3(192, 16), dim3(256), 0, stream, vt, sumv);
    hipLaunchKernelGGL(k2_fused, dim3(32, 16), dim3(256), 0, stream,
                       geb16, vt, sumv, aggb);
    hipLaunchKernelGGL(k3_ctx, dim3(3, 3, 16), dim3(256), 0, stream,
                       aggb, cw, wraw);
    hipLaunchKernelGGL(k3b_m2, dim3(96, 16), dim3(192), 0, stream,
                       wraw, wl, m2);
    hipLaunchKernelGGL(k4_simple, dim3(32768), dim3(96), 0, stream,
                       x, vt, m2, bl, out);
}

// Round 13
// 454.284 us; speedup vs baseline: 4.2347x; 1.1656x over previous
//
#include <hip/hip_runtime.h>
#include <hip/hip_bf16.h>

// B=16, C=2048, T=128, ID=32, NC=16, CD=32, GD=32, OUT=96, GIN=192
// ws (floats): vt(bf16) @0 (3,145,728) | geb16(bf16) @3145728 (524,288) |
// aggb(bf16) @3670016 (3,145,728) | wraw @6815744 (589,824) |
// m2 @7405568 (294,912) | sumv @7700480 (3,072) |
// wpart @7703552 (4,718,592, only if ws_size permits) => 49.7 MB (or 30.8).
//
// ADJACENCY SEMANTICS: weight(m) = 0 if m==o; exp(s) if s>0; 1 if s<=0.
// Decomposition: d = weight-1 (d=-1 diag, exp(s)-1 if s>0, else 0).
// agg_unnorm = sumV + MFMA(d,V);  l = 2048 + sum(d).
// Round-13: k3_ctx was 144 blocks on 256 CUs (6.5% occupancy, 128us).
// Split-K x8 (1152 blocks) + fp32 partials + reduce/tanh kernel.

typedef __attribute__((ext_vector_type(8))) short short8;
typedef __attribute__((ext_vector_type(16))) float f32x16;

__device__ __forceinline__ unsigned short f2bf(float f) {
    __hip_bfloat16 h = __float2bfloat16(f);
    return *reinterpret_cast<unsigned short*>(&h);
}
__device__ __forceinline__ float bf2f(unsigned short u) {
    __hip_bfloat16 h = *reinterpret_cast<__hip_bfloat16*>(&u);
    return __bfloat162float(h);
}

// ---------------------------------------------------------------------------
// k0: transpose x (fp32 [b][m][128]) -> VT bf16 [b][ch][m] for ch 0..127.
// ---------------------------------------------------------------------------
__global__ __launch_bounds__(256) void k0_transpose_x(
    const float* __restrict__ x, unsigned short* __restrict__ vt)
{
    __shared__ float sT[64 * 133];
    const int t = threadIdx.x;
    const int m0 = blockIdx.x * 64;
    const int b = blockIdx.y;
    const float* xb = x + (size_t)b * 2048 * 128;
    #pragma unroll
    for (int kk = 0; kk < 8; ++kk) {
        int i = t + kk * 256;
        int mm = i >> 5, q4 = i & 31;
        float4 v = ((const float4*)(xb + (size_t)(m0 + mm) * 128))[q4];
        float* d = sT + mm * 133 + q4 * 4;
        d[0] = v.x; d[1] = v.y; d[2] = v.z; d[3] = v.w;
    }
    __syncthreads();
    const int mp = t & 31;
    const int ch0 = t >> 5;
    #pragma unroll
    for (int pass = 0; pass < 16; ++pass) {
        int ch = ch0 + pass * 8;
        unsigned int u0 = f2bf(sT[(2 * mp) * 133 + ch]);
        unsigned int u1 = f2bf(sT[(2 * mp + 1) * 133 + ch]);
        *((unsigned int*)(vt + (size_t)(b * 192 + ch) * 2048 + m0) + mp) =
            u0 | (u1 << 16);
    }
}

// ---------------------------------------------------------------------------
// k1: per-row features. One block (128 thr) per row r. Writes VT channels
// 128..191 (bf16) and ge row as bf16 (for the MFMA S phase).
// ---------------------------------------------------------------------------
__global__ __launch_bounds__(128) void k1_simple(
    const float* __restrict__ x, const float* __restrict__ id_emb,
    const float* __restrict__ w1, const float* __restrict__ b1,
    const float* __restrict__ w2, const float* __restrict__ b2,
    const float* __restrict__ ce, const float* __restrict__ wic,
    const float* __restrict__ bic, const float* __restrict__ wg,
    const float* __restrict__ bg, unsigned short* __restrict__ vt,
    unsigned short* __restrict__ geb16)
{
    __shared__ float sx[128];
    __shared__ float sh[64];
    __shared__ float sid[32];
    __shared__ float sic[32];
    __shared__ float sp[16];
    __shared__ float scl[32];

    const int r = blockIdx.x;
    const int b = r >> 11;
    const int c = r & 2047;
    const int t = threadIdx.x;

    sx[t] = x[(size_t)r * 128 + t];
    __syncthreads();

    if (t < 64) {
        float a = b1[t];
        for (int k = 0; k < 128; ++k) a = fmaf(sx[k], w1[k * 64 + t], a);
        sh[t] = fmaxf(a, 0.f);
    }
    __syncthreads();

    if (t < 32) {
        float a = b2[t];
        for (int k = 0; k < 64; ++k) a = fmaf(sh[k], w2[k * 32 + t], a);
        float ide = id_emb[c * 32 + t] + a;
        sid[t] = ide;
        vt[(size_t)(b * 192 + 128 + t) * 2048 + c] = f2bf(ide);
    }
    __syncthreads();

    if (t < 32) {
        float a = bic[t];
        for (int k = 0; k < 32; ++k) a = fmaf(sid[k], wic[k * 32 + t], a);
        sic[t] = a;
    }
    __syncthreads();

    if (t < 16) {
        float a = 0.f;
        for (int k = 0; k < 32; ++k) a = fmaf(sic[k], ce[t * 32 + k], a);
        sp[t] = a;
    }
    __syncthreads();

    if (t == 0) {
        float mx = sp[0];
        for (int n = 1; n < 16; ++n) mx = fmaxf(mx, sp[n]);
        float ss = 0.f;
        for (int n = 0; n < 16; ++n) { float e = __expf(sp[n] - mx); sp[n] = e; ss += e; }
        float inv = 1.f / ss;
        for (int n = 0; n < 16; ++n) sp[n] *= inv;
    }
    __syncthreads();

    if (t < 32) {
        float a = 0.f;
        for (int n = 0; n < 16; ++n) a = fmaf(sp[n], ce[n * 32 + t], a);
        scl[t] = a;
        vt[(size_t)(b * 192 + 160 + t) * 2048 + c] = f2bf(a);
    }
    __syncthreads();

    if (t < 32) {
        float a = bg[t];
        for (int k = 0; k < 32; ++k) a = fmaf(sid[k], wg[k * 32 + t], a);
        for (int k = 0; k < 32; ++k) a = fmaf(scl[k], wg[(32 + k) * 32 + t], a);
        geb16[(size_t)r * 32 + t] = f2bf(a);
    }
}

// ---------------------------------------------------------------------------
// k1b: sumV[b][ch] = sum_m VT[b][ch][m] (fp32 accumulate of bf16).
// ---------------------------------------------------------------------------
__global__ __launch_bounds__(256) void k1b_sumv(
    const unsigned short* __restrict__ vt, float* __restrict__ sumv)
{
    __shared__ float red[256];
    const int ch = blockIdx.x, b = blockIdx.y, t = threadIdx.x;
    const unsigned short* row = vt + (size_t)(b * 192 + ch) * 2048;
    float a = 0.f;
    #pragma unroll
    for (int j = 0; j < 8; ++j) a += bf2f(row[t * 8 + j]);
    red[t] = a; __syncthreads();
    for (int off = 128; off > 0; off >>= 1) {
        if (t < off) red[t] += red[t + off];
        __syncthreads();
    }
    if (t == 0) sumv[b * 192 + ch] = red[0];
}

// ---------------------------------------------------------------------------
// k2: all-MFMA core. Epilogue writes normalized agg to aggb (plain stores).
// s_buf = 9472 floats: sGeO(1280)|sGe(1280)|sVt(6912); lpbuf aliases front.
// ---------------------------------------------------------------------------
__global__ __launch_bounds__(256) void k2_fused(
    const unsigned short* __restrict__ geb16,
    const unsigned short* __restrict__ vt,
    const float* __restrict__ sumv,
    unsigned short* __restrict__ aggb)
{
    __shared__ float s_buf[9472];
    __shared__ float sinv[64];
    __shared__ float s_sum[192];
    __shared__ unsigned short dw[64 * 72];
    unsigned short* sGeO = (unsigned short*)(s_buf);          // [64][40] bf16
    unsigned short* sGe  = (unsigned short*)(s_buf + 1280);   // [64][40] bf16
    unsigned short* sVt  = (unsigned short*)(s_buf + 2560);   // [192][72] bf16
    float* lpbuf = s_buf;                                     // [64][68] post-loop

    const int t = threadIdx.x;
    const int b = blockIdx.y;
    const int o0 = blockIdx.x * 64;
    const unsigned short* geb = geb16 + (size_t)b * 2048 * 32;
    const unsigned short* vtb = vt + (size_t)b * 192 * 2048;

    const int lane = t & 63;
    const int mg = t >> 6;
    const int col = lane & 31;
    const int grp = lane >> 5;
    const int os = (mg & 1) * 32;
    const int ms = (mg >> 1) * 32;
    const int orow0 = (mg & 1) * 32;
    const int dbase = (mg >> 1) * 96;

    if (t < 192) s_sum[t] = sumv[b * 192 + t];

    {
        int row = t >> 2, c8 = t & 3;
        short8 v = *(const short8*)(geb + (size_t)(o0 + row) * 32 + c8 * 8);
        *(short8*)(sGeO + row * 40 + c8 * 8) = v;
    }

    f32x16 acc0, acc1, acc2;
    #pragma unroll
    for (int i = 0; i < 16; ++i) { acc0[i] = 0.f; acc1[i] = 0.f; acc2[i] = 0.f; }
    float lpA[16];
    #pragma unroll
    for (int i = 0; i < 16; ++i) lpA[i] = 0.f;

    for (int m0 = 0; m0 < 2048; m0 += 64) {
        {
            int row = t >> 2, c8 = t & 3;
            short8 v = *(const short8*)(geb + (size_t)(m0 + row) * 32 + c8 * 8);
            *(short8*)(sGe + row * 40 + c8 * 8) = v;
        }
        #pragma unroll
        for (int kk = 0; kk < 6; ++kk) {
            int i = t + kk * 256;
            int ch = i >> 3, m8 = i & 7;
            short8 v = *(const short8*)(vtb + (size_t)ch * 2048 + m0 + m8 * 8);
            *(short8*)(sVt + ch * 72 + m8 * 8) = v;
        }
        __syncthreads();

        f32x16 sacc;
        #pragma unroll
        for (int i = 0; i < 16; ++i) sacc[i] = 0.f;
        #pragma unroll
        for (int ks = 0; ks < 2; ++ks) {
            short8 A  = *(const short8*)(sGeO + (os + col) * 40 + ks * 16 + grp * 8);
            short8 Bf = *(const short8*)(sGe + (ms + col) * 40 + ks * 16 + grp * 8);
            sacc = __builtin_amdgcn_mfma_f32_32x32x16_bf16(A, Bf, sacc, 0, 0, 0);
        }
        {
            const int m_local = ms + col;
            const int gm = m0 + m_local;
            #pragma unroll
            for (int r = 0; r < 16; ++r) {
                int o_local = os + (r & 3) + 8 * (r >> 2) + 4 * grp;
                float s = sacc[r];
                float d = (gm == o0 + o_local) ? -1.f
                        : ((s > 0.f) ? (__expf(s) - 1.f) : 0.f);
                lpA[r] += d;
                dw[o_local * 72 + m_local] = f2bf(d);
            }
        }
        __syncthreads();

        #pragma unroll
        for (int ks = 0; ks < 4; ++ks) {
            short8 A  = *(const short8*)(dw + (orow0 + col) * 72 + ks * 16 + grp * 8);
            short8 B0 = *(const short8*)(sVt + (dbase + col) * 72 + ks * 16 + grp * 8);
            short8 B1 = *(const short8*)(sVt + (dbase + 32 + col) * 72 + ks * 16 + grp * 8);
            short8 B2 = *(const short8*)(sVt + (dbase + 64 + col) * 72 + ks * 16 + grp * 8);
            acc0 = __builtin_amdgcn_mfma_f32_32x32x16_bf16(A, B0, acc0, 0, 0, 0);
            acc1 = __builtin_amdgcn_mfma_f32_32x32x16_bf16(A, B1, acc1, 0, 0, 0);
            acc2 = __builtin_amdgcn_mfma_f32_32x32x16_bf16(A, B2, acc2, 0, 0, 0);
        }
        __syncthreads();
    }

    {
        const int widx = mg >> 1;
        #pragma unroll
        for (int r = 0; r < 16; ++r) {
            int ol = os + (r & 3) + 8 * (r >> 2) + 4 * grp;
            lpbuf[(widx * 32 + col) * 68 + ol] = lpA[r];
        }
    }
    __syncthreads();
    if (t < 64) {
        float l = 2048.f;
        for (int i = 0; i < 64; ++i) l += lpbuf[i * 68 + t];
        sinv[t] = 1.f / l;
    }
    __syncthreads();

    {
        f32x16 av[3] = {acc0, acc1, acc2};
        unsigned short* ab = aggb + (size_t)b * 2048 * 192;
        #pragma unroll
        for (int n = 0; n < 3; ++n) {
            int chn = dbase + n * 32 + col;
            float sv = s_sum[chn];
            #pragma unroll
            for (int r = 0; r < 16; ++r) {
                int ol = orow0 + (r & 3) + 8 * (r >> 2) + 4 * grp;
                ab[(size_t)(o0 + ol) * 192 + chn] =
                    f2bf((sv + av[n][r]) * sinv[ol]);
            }
        }
    }
}

// ---------------------------------------------------------------------------
// k3_ctx_sk: split-K partial of w-sum. blockIdx.z = b*8+ks; K range
// [ks*256, +256). Writes fp32 partial (no tanh) to wpart[slot].
// ---------------------------------------------------------------------------
__global__ __launch_bounds__(256) void k3_ctx_sk(
    const unsigned short* __restrict__ aggb, const float* __restrict__ cw,
    float* __restrict__ wpart)
{
    __shared__ float sA[64 * 68];
    __shared__ float sW[64 * 68];
    const int t = threadIdx.x;
    const int slot = blockIdx.z;          // b*8 + ks
    const int b = slot >> 3;
    const int ks = slot & 7;
    const int d0 = blockIdx.x * 64;
    const int l0 = blockIdx.y * 64;
    const unsigned short* ab = aggb + (size_t)b * 2048 * 192;
    const int ti = t >> 4, tj = t & 15;
    float acc[4][4] = {{0.f}};

    for (int o0 = ks * 256; o0 < ks * 256 + 256; o0 += 64) {
        for (int i = t; i < 4096; i += 256) {
            int oo = i >> 6, dd = i & 63;
            sA[oo * 68 + dd] = bf2f(ab[(size_t)(o0 + oo) * 192 + d0 + dd]);
            sW[oo * 68 + dd] = cw[(size_t)(o0 + oo) * 192 + l0 + dd];
        }
        __syncthreads();
        for (int o = 0; o < 64; ++o) {
            const float* ap = sA + o * 68 + ti * 4;
            const float* wp = sW + o * 68 + tj * 4;
            float a0 = ap[0], a1 = ap[1], a2 = ap[2], a3 = ap[3];
            float w0 = wp[0], w1v = wp[1], w2v = wp[2], w3 = wp[3];
            acc[0][0] = fmaf(a0, w0, acc[0][0]); acc[0][1] = fmaf(a0, w1v, acc[0][1]);
            acc[0][2] = fmaf(a0, w2v, acc[0][2]); acc[0][3] = fmaf(a0, w3, acc[0][3]);
            acc[1][0] = fmaf(a1, w0, acc[1][0]); acc[1][1] = fmaf(a1, w1v, acc[1][1]);
            acc[1][2] = fmaf(a1, w2v, acc[1][2]); acc[1][3] = fmaf(a1, w3, acc[1][3]);
            acc[2][0] = fmaf(a2, w0, acc[2][0]); acc[2][1] = fmaf(a2, w1v, acc[2][1]);
            acc[2][2] = fmaf(a2, w2v, acc[2][2]); acc[2][3] = fmaf(a2, w3, acc[2][3]);
            acc[3][0] = fmaf(a3, w0, acc[3][0]); acc[3][1] = fmaf(a3, w1v, acc[3][1]);
            acc[3][2] = fmaf(a3, w2v, acc[3][2]); acc[3][3] = fmaf(a3, w3, acc[3][3]);
        }
        __syncthreads();
    }
    float* wp = wpart + (size_t)slot * 36864;
    #pragma unroll
    for (int i = 0; i < 4; ++i)
        #pragma unroll
        for (int j = 0; j < 4; ++j)
            wp[(d0 + ti * 4 + i) * 192 + l0 + tj * 4 + j] = acc[i][j];
}

// ---------------------------------------------------------------------------
// k3r: wraw[b][idx] = tanh(sum_ks wpart[b*8+ks][idx])
// ---------------------------------------------------------------------------
__global__ __launch_bounds__(256) void k3r_reduce(
    const float* __restrict__ wpart, float* __restrict__ wraw)
{
    const int idx = blockIdx.x * 256 + threadIdx.x;   // 0..36863
    const int b = blockIdx.y;
    const float* base = wpart + (size_t)b * 8 * 36864 + idx;
    float a = 0.f;
    #pragma unroll
    for (int ks = 0; ks < 8; ++ks) a += base[(size_t)ks * 36864];
    wraw[(size_t)b * 36864 + idx] = tanhf(a);
}

// ---------------------------------------------------------------------------
// k3_ctx: single-pass fallback (used only if ws too small for wpart).
// ---------------------------------------------------------------------------
__global__ __launch_bounds__(256) void k3_ctx(
    const unsigned short* __restrict__ aggb, const float* __restrict__ cw,
    float* __restrict__ wraw)
{
    __shared__ float sA[64 * 68];
    __shared__ float sW[64 * 68];
    const int t = threadIdx.x;
    const int b = blockIdx.z;
    const int d0 = blockIdx.x * 64;
    const int l0 = blockIdx.y * 64;
    const unsigned short* ab = aggb + (size_t)b * 2048 * 192;
    const int ti = t >> 4, tj = t & 15;
    float acc[4][4] = {{0.f}};

    for (int o0 = 0; o0 < 2048; o0 += 64) {
        for (int i = t; i < 4096; i += 256) {
            int oo = i >> 6, dd = i & 63;
            sA[oo * 68 + dd] = bf2f(ab[(size_t)(o0 + oo) * 192 + d0 + dd]);
            sW[oo * 68 + dd] = cw[(size_t)(o0 + oo) * 192 + l0 + dd];
        }
        __syncthreads();
        for (int o = 0; o < 64; ++o) {
            const float* ap = sA + o * 68 + ti * 4;
            const float* wp = sW + o * 68 + tj * 4;
            float a0 = ap[0], a1 = ap[1], a2 = ap[2], a3 = ap[3];
            float w0 = wp[0], w1v = wp[1], w2v = wp[2], w3 = wp[3];
            acc[0][0] = fmaf(a0, w0, acc[0][0]); acc[0][1] = fmaf(a0, w1v, acc[0][1]);
            acc[0][2] = fmaf(a0, w2v, acc[0][2]); acc[0][3] = fmaf(a0, w3, acc[0][3]);
            acc[1][0] = fmaf(a1, w0, acc[1][0]); acc[1][1] = fmaf(a1, w1v, acc[1][1]);
            acc[1][2] = fmaf(a1, w2v, acc[1][2]); acc[1][3] = fmaf(a1, w3, acc[1][3]);
            acc[2][0] = fmaf(a2, w0, acc[2][0]); acc[2][1] = fmaf(a2, w1v, acc[2][1]);
            acc[2][2] = fmaf(a2, w2v, acc[2][2]); acc[2][3] = fmaf(a2, w3, acc[2][3]);
            acc[3][0] = fmaf(a3, w0, acc[3][0]); acc[3][1] = fmaf(a3, w1v, acc[3][1]);
            acc[3][2] = fmaf(a3, w2v, acc[3][2]); acc[3][3] = fmaf(a3, w3, acc[3][3]);
        }
        __syncthreads();
    }
    float* wb = wraw + (size_t)b * 36864;
    #pragma unroll
    for (int i = 0; i < 4; ++i)
        #pragma unroll
        for (int j = 0; j < 4; ++j)
            wb[(d0 + ti * 4 + i) * 192 + l0 + tj * 4 + j] = tanhf(acc[i][j]);
}

// ---------------------------------------------------------------------------
__global__ __launch_bounds__(192) void k3b_m2(
    const float* __restrict__ wmat, const float* __restrict__ wl,
    float* __restrict__ m2)
{
    const int t = threadIdx.x;
    const int b = blockIdx.y;
    const int d = blockIdx.x * 2 + (t / 96);
    const int l = t % 96;
    const float* wrow = wmat + (size_t)b * 36864 + d * 192;
    float acc = wl[d * 96 + l];
    for (int k = 0; k < 192; ++k)
        acc = fmaf(wrow[k], wl[k * 96 + l], acc);
    m2[(size_t)b * 18432 + d * 96 + l] = acc;
}

// ---------------------------------------------------------------------------
// k4: out[r][l] = [x_row | ext_row(from VT bf16)] . M2[b][:,l] + bl[l]
// ---------------------------------------------------------------------------
__global__ __launch_bounds__(96) void k4_simple(
    const float* __restrict__ x, const unsigned short* __restrict__ vt,
    const float* __restrict__ m2, const float* __restrict__ bl,
    float* __restrict__ out)
{
    __shared__ float sx[128];
    __shared__ float sxe[64];
    const int r = blockIdx.x;
    const int b = r >> 11;
    const int c = r & 2047;
    const int t = threadIdx.x;
    for (int i = t; i < 128; i += 96) sx[i] = x[(size_t)r * 128 + i];
    if (t < 64) sxe[t] = bf2f(vt[(size_t)(b * 192 + 128 + t) * 2048 + c]);
    __syncthreads();
    const float* mb = m2 + (size_t)b * 18432;
    float a = bl[t];
    for (int k = 0; k < 128; ++k) a = fmaf(sx[k], mb[k * 96 + t], a);
    for (int k = 0; k < 64; ++k) a = fmaf(sxe[k], mb[(128 + k) * 96 + t], a);
    out[(size_t)r * 96 + t] = a;
}

// ---------------------------------------------------------------------------
extern "C" void kernel_launch(void* const* d_in, const int* in_sizes, int n_in,
                              void* d_out, int out_size, void* d_ws, size_t ws_size,
                              hipStream_t stream) {
    const float* x      = (const float*)d_in[0];
    const float* id_emb = (const float*)d_in[1];
    const float* w1     = (const float*)d_in[2];
    const float* b1     = (const float*)d_in[3];
    const float* w2     = (const float*)d_in[4];
    const float* b2     = (const float*)d_in[5];
    const float* ce     = (const float*)d_in[6];
    const float* wic    = (const float*)d_in[7];
    const float* bic    = (const float*)d_in[8];
    const float* wg     = (const float*)d_in[9];
    const float* bg     = (const float*)d_in[10];
    const float* cw     = (const float*)d_in[11];
    const float* wl     = (const float*)d_in[12];
    const float* bl     = (const float*)d_in[13];
    float* out = (float*)d_out;

    float* ws = (float*)d_ws;
    unsigned short* vt    = (unsigned short*)ws;             // 3,145,728 f-eq
    unsigned short* geb16 = (unsigned short*)(ws + 3145728); //   524,288 f-eq
    unsigned short* aggb  = (unsigned short*)(ws + 3670016); // 3,145,728 f-eq
    float* wraw  = ws + 6815744;                             //   589,824
    float* m2    = ws + 7405568;                             //   294,912
    float* sumv  = ws + 7700480;                             //     3,072
    float* wpart = ws + 7703552;                             // 4,718,592 (opt)
    const size_t need_sk = (7703552ull + 4718592ull) * 4ull; // 49.7 MB
    const bool use_sk = (ws_size >= need_sk);

    hipLaunchKernelGGL(k0_transpose_x, dim3(32, 16), dim3(256), 0, stream, x, vt);
    hipLaunchKernelGGL(k1_simple, dim3(32768), dim3(128), 0, stream,
                       x, id_emb, w1, b1, w2, b2, ce, wic, bic, wg, bg, vt, geb16);
    hipLaunchKernelGGL(k1b_sumv, dim3(192, 16), dim3(256), 0, stream, vt, sumv);
    hipLaunchKernelGGL(k2_fused, dim3(32, 16), dim3(256), 0, stream,
                       geb16, vt, sumv, aggb);
    if (use_sk) {
        hipLaunchKernelGGL(k3_ctx_sk, dim3(3, 3, 128), dim3(256), 0, stream,
                           aggb, cw, wpart);
        hipLaunchKernelGGL(k3r_reduce, dim3(144, 16), dim3(256), 0, stream,
                           wpart, wraw);
    } else {
        hipLaunchKernelGGL(k3_ctx, dim3(3, 3, 16), dim3(256), 0, stream,
                           aggb, cw, wraw);
    }
    hipLaunchKernelGGL(k3b_m2, dim3(96, 16), dim3(192), 0, stream,
                       wraw, wl, m2);
    hipLaunchKernelGGL(k4_simple, dim3(32768), dim3(96), 0, stream,
                       x, vt, m2, bl, out);
}

// Round 14
// 358.417 us; speedup vs baseline: 5.3674x; 1.2675x over previous
//
#include <hip/hip_runtime.h>
#include <hip/hip_bf16.h>

// B=16, C=2048, T=128, ID=32, NC=16, CD=32, GD=32, OUT=96, GIN=192
// ws (floats): vt(bf16) @0 (3,145,728) | geb16(bf16) @3145728 (524,288) |
// aggb(bf16) @3670016 (3,145,728) | wraw @6815744 (589,824) |
// m2 @7405568 (294,912) | sumv @7700480 (3,072) |
// wpart @7703552 (4,718,592, only if ws_size permits) => 49.7 MB (or 30.8).
//
// ADJACENCY SEMANTICS: weight(m) = 0 if m==o; exp(s) if s>0; 1 if s<=0.
// Decomposition: d = weight-1 (d=-1 diag, exp(s)-1 if s>0, else 0).
// agg_unnorm = sumV + MFMA(d,V);  l = 2048 + sum(d).
// Round-14: k1 re-tiled 32 rows/block (weight reuse 32x; was 1.8 GB L2) and
// k4 re-tiled 64 rows/block with m2 staged in LDS (reuse 64x; was 2.4 GB L2).

typedef __attribute__((ext_vector_type(8))) short short8;
typedef __attribute__((ext_vector_type(16))) float f32x16;

__device__ __forceinline__ unsigned short f2bf(float f) {
    __hip_bfloat16 h = __float2bfloat16(f);
    return *reinterpret_cast<unsigned short*>(&h);
}
__device__ __forceinline__ float bf2f(unsigned short u) {
    __hip_bfloat16 h = *reinterpret_cast<__hip_bfloat16*>(&u);
    return __bfloat162float(h);
}

// ---------------------------------------------------------------------------
// k0: transpose x (fp32 [b][m][128]) -> VT bf16 [b][ch][m] for ch 0..127.
// ---------------------------------------------------------------------------
__global__ __launch_bounds__(256) void k0_transpose_x(
    const float* __restrict__ x, unsigned short* __restrict__ vt)
{
    __shared__ float sT[64 * 133];
    const int t = threadIdx.x;
    const int m0 = blockIdx.x * 64;
    const int b = blockIdx.y;
    const float* xb = x + (size_t)b * 2048 * 128;
    #pragma unroll
    for (int kk = 0; kk < 8; ++kk) {
        int i = t + kk * 256;
        int mm = i >> 5, q4 = i & 31;
        float4 v = ((const float4*)(xb + (size_t)(m0 + mm) * 128))[q4];
        float* d = sT + mm * 133 + q4 * 4;
        d[0] = v.x; d[1] = v.y; d[2] = v.z; d[3] = v.w;
    }
    __syncthreads();
    const int mp = t & 31;
    const int ch0 = t >> 5;
    #pragma unroll
    for (int pass = 0; pass < 16; ++pass) {
        int ch = ch0 + pass * 8;
        unsigned int u0 = f2bf(sT[(2 * mp) * 133 + ch]);
        unsigned int u1 = f2bf(sT[(2 * mp + 1) * 133 + ch]);
        *((unsigned int*)(vt + (size_t)(b * 192 + ch) * 2048 + m0) + mp) =
            u0 | (u1 << 16);
    }
}

// ---------------------------------------------------------------------------
// k1_tiled: 32 rows per block (grid 1024, 256 thr). Weights read from
// global (L1-broadcast across the block); xs + intermediates in LDS with
// conflict-free pads. Math/order identical to the old k1_simple.
// ---------------------------------------------------------------------------
__global__ __launch_bounds__(256) void k1_tiled(
    const float* __restrict__ x, const float* __restrict__ id_emb,
    const float* __restrict__ w1, const float* __restrict__ b1,
    const float* __restrict__ w2, const float* __restrict__ b2,
    const float* __restrict__ ce, const float* __restrict__ wic,
    const float* __restrict__ bic, const float* __restrict__ wg,
    const float* __restrict__ bg, unsigned short* __restrict__ vt,
    unsigned short* __restrict__ geb16)
{
    __shared__ float sxs[32 * 132];   // pad 132: rows spread over banks
    __shared__ float sh[32 * 68];
    __shared__ float sid[32 * 36];
    __shared__ float sic[32 * 36];
    __shared__ float scl[32 * 36];
    __shared__ float sp[32 * 20];

    const int t = threadIdx.x;
    const int r0 = blockIdx.x * 32;     // 32-row blocks never cross a batch
    const int b = r0 >> 11;
    const int c0 = r0 & 2047;

    // Phase A: stage xs (32x128), scalar (keeps 132-pad conflict-free)
    #pragma unroll
    for (int p = 0; p < 16; ++p) {
        int i = t + p * 256;            // 0..4095
        int row = i >> 7, k = i & 127;
        sxs[row * 132 + k] = x[(size_t)r0 * 128 + i];
    }
    __syncthreads();

    // Phase B: h = relu(xs@w1 + b1). row=t>>3, 8 cols per thread.
    {
        const int row = t >> 3, j0 = (t & 7) * 8;
        float acc[8];
        #pragma unroll
        for (int j = 0; j < 8; ++j) acc[j] = b1[j0 + j];
        for (int k = 0; k < 128; ++k) {
            float xv = sxs[row * 132 + k];
            const float4* wr = (const float4*)(w1 + k * 64 + j0);
            float4 wa = wr[0], wb = wr[1];
            acc[0] = fmaf(xv, wa.x, acc[0]); acc[1] = fmaf(xv, wa.y, acc[1]);
            acc[2] = fmaf(xv, wa.z, acc[2]); acc[3] = fmaf(xv, wa.w, acc[3]);
            acc[4] = fmaf(xv, wb.x, acc[4]); acc[5] = fmaf(xv, wb.y, acc[5]);
            acc[6] = fmaf(xv, wb.z, acc[6]); acc[7] = fmaf(xv, wb.w, acc[7]);
        }
        float* hr = sh + row * 68 + j0;
        #pragma unroll
        for (int j = 0; j < 8; ++j) hr[j] = fmaxf(acc[j], 0.f);
    }
    __syncthreads();

    // Phase C: ide = id_emb + h@w2 + b2. row=t>>3, 4 cols per thread.
    {
        const int row = t >> 3, j0 = (t & 7) * 4;
        const int c = c0 + row, r = r0 + row;
        float acc[4];
        #pragma unroll
        for (int j = 0; j < 4; ++j) acc[j] = b2[j0 + j];
        for (int k = 0; k < 64; ++k) {
            float hv = sh[row * 68 + k];
            const float4 wv = *(const float4*)(w2 + k * 32 + j0);
            acc[0] = fmaf(hv, wv.x, acc[0]); acc[1] = fmaf(hv, wv.y, acc[1]);
            acc[2] = fmaf(hv, wv.z, acc[2]); acc[3] = fmaf(hv, wv.w, acc[3]);
        }
        #pragma unroll
        for (int j = 0; j < 4; ++j) {
            float ide = id_emb[c * 32 + j0 + j] + acc[j];
            sid[row * 36 + j0 + j] = ide;
            vt[(size_t)(b * 192 + 128 + j0 + j) * 2048 + c] = f2bf(ide);
        }
    }
    __syncthreads();

    // Phase D: ic = id_e@wic + bic. Same mapping.
    {
        const int row = t >> 3, j0 = (t & 7) * 4;
        float acc[4];
        #pragma unroll
        for (int j = 0; j < 4; ++j) acc[j] = bic[j0 + j];
        for (int k = 0; k < 32; ++k) {
            float iv = sid[row * 36 + k];
            const float4 wv = *(const float4*)(wic + k * 32 + j0);
            acc[0] = fmaf(iv, wv.x, acc[0]); acc[1] = fmaf(iv, wv.y, acc[1]);
            acc[2] = fmaf(iv, wv.z, acc[2]); acc[3] = fmaf(iv, wv.w, acc[3]);
        }
        #pragma unroll
        for (int j = 0; j < 4; ++j) sic[row * 36 + j0 + j] = acc[j];
    }
    __syncthreads();

    // Phase E: logits. n=t&15, rows t>>4 and (t>>4)+16.
    {
        const int n = t & 15, rowp = t >> 4;
        #pragma unroll
        for (int h = 0; h < 2; ++h) {
            int row = rowp + h * 16;
            float a = 0.f;
            for (int k = 0; k < 32; ++k)
                a = fmaf(sic[row * 36 + k], ce[n * 32 + k], a);
            sp[row * 20 + n] = a;
        }
    }
    __syncthreads();

    // Phase F: softmax over 16 clusters, one thread per row (serial).
    if (t < 32) {
        float* pr = sp + t * 20;
        float mx = pr[0];
        for (int n = 1; n < 16; ++n) mx = fmaxf(mx, pr[n]);
        float ss = 0.f;
        for (int n = 0; n < 16; ++n) { float e = __expf(pr[n] - mx); pr[n] = e; ss += e; }
        float inv = 1.f / ss;
        for (int n = 0; n < 16; ++n) pr[n] *= inv;
    }
    __syncthreads();

    // Phase G: cl = p@ce. row=t>>3, 4 cols per thread.
    {
        const int row = t >> 3, j0 = (t & 7) * 4;
        const int c = c0 + row;
        float acc[4] = {0.f, 0.f, 0.f, 0.f};
        for (int n = 0; n < 16; ++n) {
            float pv = sp[row * 20 + n];
            const float4 cv = *(const float4*)(ce + n * 32 + j0);
            acc[0] = fmaf(pv, cv.x, acc[0]); acc[1] = fmaf(pv, cv.y, acc[1]);
            acc[2] = fmaf(pv, cv.z, acc[2]); acc[3] = fmaf(pv, cv.w, acc[3]);
        }
        #pragma unroll
        for (int j = 0; j < 4; ++j) {
            scl[row * 36 + j0 + j] = acc[j];
            vt[(size_t)(b * 192 + 160 + j0 + j) * 2048 + c] = f2bf(acc[j]);
        }
    }
    __syncthreads();

    // Phase H: ge = [id|cl]@wg + bg -> bf16. row=t>>3, 4 cols per thread.
    {
        const int row = t >> 3, j0 = (t & 7) * 4;
        const int r = r0 + row;
        float acc[4];
        #pragma unroll
        for (int j = 0; j < 4; ++j) acc[j] = bg[j0 + j];
        for (int k = 0; k < 32; ++k) {
            float iv = sid[row * 36 + k];
            const float4 wv = *(const float4*)(wg + k * 32 + j0);
            acc[0] = fmaf(iv, wv.x, acc[0]); acc[1] = fmaf(iv, wv.y, acc[1]);
            acc[2] = fmaf(iv, wv.z, acc[2]); acc[3] = fmaf(iv, wv.w, acc[3]);
        }
        for (int k = 0; k < 32; ++k) {
            float cv2 = scl[row * 36 + k];
            const float4 wv = *(const float4*)(wg + (32 + k) * 32 + j0);
            acc[0] = fmaf(cv2, wv.x, acc[0]); acc[1] = fmaf(cv2, wv.y, acc[1]);
            acc[2] = fmaf(cv2, wv.z, acc[2]); acc[3] = fmaf(cv2, wv.w, acc[3]);
        }
        #pragma unroll
        for (int j = 0; j < 4; ++j)
            geb16[(size_t)r * 32 + j0 + j] = f2bf(acc[j]);
    }
}

// ---------------------------------------------------------------------------
// k1b: sumV[b][ch] = sum_m VT[b][ch][m] (fp32 accumulate of bf16).
// ---------------------------------------------------------------------------
__global__ __launch_bounds__(256) void k1b_sumv(
    const unsigned short* __restrict__ vt, float* __restrict__ sumv)
{
    __shared__ float red[256];
    const int ch = blockIdx.x, b = blockIdx.y, t = threadIdx.x;
    const unsigned short* row = vt + (size_t)(b * 192 + ch) * 2048;
    float a = 0.f;
    #pragma unroll
    for (int j = 0; j < 8; ++j) a += bf2f(row[t * 8 + j]);
    red[t] = a; __syncthreads();
    for (int off = 128; off > 0; off >>= 1) {
        if (t < off) red[t] += red[t + off];
        __syncthreads();
    }
    if (t == 0) sumv[b * 192 + ch] = red[0];
}

// ---------------------------------------------------------------------------
// k2: all-MFMA core. Epilogue writes normalized agg to aggb (plain stores).
// s_buf = 9472 floats: sGeO(1280)|sGe(1280)|sVt(6912); lpbuf aliases front.
// ---------------------------------------------------------------------------
__global__ __launch_bounds__(256) void k2_fused(
    const unsigned short* __restrict__ geb16,
    const unsigned short* __restrict__ vt,
    const float* __restrict__ sumv,
    unsigned short* __restrict__ aggb)
{
    __shared__ float s_buf[9472];
    __shared__ float sinv[64];
    __shared__ float s_sum[192];
    __shared__ unsigned short dw[64 * 72];
    unsigned short* sGeO = (unsigned short*)(s_buf);          // [64][40] bf16
    unsigned short* sGe  = (unsigned short*)(s_buf + 1280);   // [64][40] bf16
    unsigned short* sVt  = (unsigned short*)(s_buf + 2560);   // [192][72] bf16
    float* lpbuf = s_buf;                                     // [64][68] post-loop

    const int t = threadIdx.x;
    const int b = blockIdx.y;
    const int o0 = blockIdx.x * 64;
    const unsigned short* geb = geb16 + (size_t)b * 2048 * 32;
    const unsigned short* vtb = vt + (size_t)b * 192 * 2048;

    const int lane = t & 63;
    const int mg = t >> 6;
    const int col = lane & 31;
    const int grp = lane >> 5;
    const int os = (mg & 1) * 32;
    const int ms = (mg >> 1) * 32;
    const int orow0 = (mg & 1) * 32;
    const int dbase = (mg >> 1) * 96;

    if (t < 192) s_sum[t] = sumv[b * 192 + t];

    {
        int row = t >> 2, c8 = t & 3;
        short8 v = *(const short8*)(geb + (size_t)(o0 + row) * 32 + c8 * 8);
        *(short8*)(sGeO + row * 40 + c8 * 8) = v;
    }

    f32x16 acc0, acc1, acc2;
    #pragma unroll
    for (int i = 0; i < 16; ++i) { acc0[i] = 0.f; acc1[i] = 0.f; acc2[i] = 0.f; }
    float lpA[16];
    #pragma unroll
    for (int i = 0; i < 16; ++i) lpA[i] = 0.f;

    for (int m0 = 0; m0 < 2048; m0 += 64) {
        {
            int row = t >> 2, c8 = t & 3;
            short8 v = *(const short8*)(geb + (size_t)(m0 + row) * 32 + c8 * 8);
            *(short8*)(sGe + row * 40 + c8 * 8) = v;
        }
        #pragma unroll
        for (int kk = 0; kk < 6; ++kk) {
            int i = t + kk * 256;
            int ch = i >> 3, m8 = i & 7;
            short8 v = *(const short8*)(vtb + (size_t)ch * 2048 + m0 + m8 * 8);
            *(short8*)(sVt + ch * 72 + m8 * 8) = v;
        }
        __syncthreads();

        f32x16 sacc;
        #pragma unroll
        for (int i = 0; i < 16; ++i) sacc[i] = 0.f;
        #pragma unroll
        for (int ks = 0; ks < 2; ++ks) {
            short8 A  = *(const short8*)(sGeO + (os + col) * 40 + ks * 16 + grp * 8);
            short8 Bf = *(const short8*)(sGe + (ms + col) * 40 + ks * 16 + grp * 8);
            sacc = __builtin_amdgcn_mfma_f32_32x32x16_bf16(A, Bf, sacc, 0, 0, 0);
        }
        {
            const int m_local = ms + col;
            const int gm = m0 + m_local;
            #pragma unroll
            for (int r = 0; r < 16; ++r) {
                int o_local = os + (r & 3) + 8 * (r >> 2) + 4 * grp;
                float s = sacc[r];
                float d = (gm == o0 + o_local) ? -1.f
                        : ((s > 0.f) ? (__expf(s) - 1.f) : 0.f);
                lpA[r] += d;
                dw[o_local * 72 + m_local] = f2bf(d);
            }
        }
        __syncthreads();

        #pragma unroll
        for (int ks = 0; ks < 4; ++ks) {
            short8 A  = *(const short8*)(dw + (orow0 + col) * 72 + ks * 16 + grp * 8);
            short8 B0 = *(const short8*)(sVt + (dbase + col) * 72 + ks * 16 + grp * 8);
            short8 B1 = *(const short8*)(sVt + (dbase + 32 + col) * 72 + ks * 16 + grp * 8);
            short8 B2 = *(const short8*)(sVt + (dbase + 64 + col) * 72 + ks * 16 + grp * 8);
            acc0 = __builtin_amdgcn_mfma_f32_32x32x16_bf16(A, B0, acc0, 0, 0, 0);
            acc1 = __builtin_amdgcn_mfma_f32_32x32x16_bf16(A, B1, acc1, 0, 0, 0);
            acc2 = __builtin_amdgcn_mfma_f32_32x32x16_bf16(A, B2, acc2, 0, 0, 0);
        }
        __syncthreads();
    }

    {
        const int widx = mg >> 1;
        #pragma unroll
        for (int r = 0; r < 16; ++r) {
            int ol = os + (r & 3) + 8 * (r >> 2) + 4 * grp;
            lpbuf[(widx * 32 + col) * 68 + ol] = lpA[r];
        }
    }
    __syncthreads();
    if (t < 64) {
        float l = 2048.f;
        for (int i = 0; i < 64; ++i) l += lpbuf[i * 68 + t];
        sinv[t] = 1.f / l;
    }
    __syncthreads();

    {
        f32x16 av[3] = {acc0, acc1, acc2};
        unsigned short* ab = aggb + (size_t)b * 2048 * 192;
        #pragma unroll
        for (int n = 0; n < 3; ++n) {
            int chn = dbase + n * 32 + col;
            float sv = s_sum[chn];
            #pragma unroll
            for (int r = 0; r < 16; ++r) {
                int ol = orow0 + (r & 3) + 8 * (r >> 2) + 4 * grp;
                ab[(size_t)(o0 + ol) * 192 + chn] =
                    f2bf((sv + av[n][r]) * sinv[ol]);
            }
        }
    }
}

// ---------------------------------------------------------------------------
// k3_ctx_sk: split-K partial of w-sum. blockIdx.z = b*8+ks.
// ---------------------------------------------------------------------------
__global__ __launch_bounds__(256) void k3_ctx_sk(
    const unsigned short* __restrict__ aggb, const float* __restrict__ cw,
    float* __restrict__ wpart)
{
    __shared__ float sA[64 * 68];
    __shared__ float sW[64 * 68];
    const int t = threadIdx.x;
    const int slot = blockIdx.z;
    const int b = slot >> 3;
    const int ks = slot & 7;
    const int d0 = blockIdx.x * 64;
    const int l0 = blockIdx.y * 64;
    const unsigned short* ab = aggb + (size_t)b * 2048 * 192;
    const int ti = t >> 4, tj = t & 15;
    float acc[4][4] = {{0.f}};

    for (int o0 = ks * 256; o0 < ks * 256 + 256; o0 += 64) {
        for (int i = t; i < 4096; i += 256) {
            int oo = i >> 6, dd = i & 63;
            sA[oo * 68 + dd] = bf2f(ab[(size_t)(o0 + oo) * 192 + d0 + dd]);
            sW[oo * 68 + dd] = cw[(size_t)(o0 + oo) * 192 + l0 + dd];
        }
        __syncthreads();
        for (int o = 0; o < 64; ++o) {
            const float* ap = sA + o * 68 + ti * 4;
            const float* wp = sW + o * 68 + tj * 4;
            float a0 = ap[0], a1 = ap[1], a2 = ap[2], a3 = ap[3];
            float w0 = wp[0], w1v = wp[1], w2v = wp[2], w3 = wp[3];
            acc[0][0] = fmaf(a0, w0, acc[0][0]); acc[0][1] = fmaf(a0, w1v, acc[0][1]);
            acc[0][2] = fmaf(a0, w2v, acc[0][2]); acc[0][3] = fmaf(a0, w3, acc[0][3]);
            acc[1][0] = fmaf(a1, w0, acc[1][0]); acc[1][1] = fmaf(a1, w1v, acc[1][1]);
            acc[1][2] = fmaf(a1, w2v, acc[1][2]); acc[1][3] = fmaf(a1, w3, acc[1][3]);
            acc[2][0] = fmaf(a2, w0, acc[2][0]); acc[2][1] = fmaf(a2, w1v, acc[2][1]);
            acc[2][2] = fmaf(a2, w2v, acc[2][2]); acc[2][3] = fmaf(a2, w3, acc[2][3]);
            acc[3][0] = fmaf(a3, w0, acc[3][0]); acc[3][1] = fmaf(a3, w1v, acc[3][1]);
            acc[3][2] = fmaf(a3, w2v, acc[3][2]); acc[3][3] = fmaf(a3, w3, acc[3][3]);
        }
        __syncthreads();
    }
    float* wp = wpart + (size_t)slot * 36864;
    #pragma unroll
    for (int i = 0; i < 4; ++i)
        #pragma unroll
        for (int j = 0; j < 4; ++j)
            wp[(d0 + ti * 4 + i) * 192 + l0 + tj * 4 + j] = acc[i][j];
}

// ---------------------------------------------------------------------------
__global__ __launch_bounds__(256) void k3r_reduce(
    const float* __restrict__ wpart, float* __restrict__ wraw)
{
    const int idx = blockIdx.x * 256 + threadIdx.x;
    const int b = blockIdx.y;
    const float* base = wpart + (size_t)b * 8 * 36864 + idx;
    float a = 0.f;
    #pragma unroll
    for (int ks = 0; ks < 8; ++ks) a += base[(size_t)ks * 36864];
    wraw[(size_t)b * 36864 + idx] = tanhf(a);
}

// ---------------------------------------------------------------------------
// k3_ctx: single-pass fallback (used only if ws too small for wpart).
// ---------------------------------------------------------------------------
__global__ __launch_bounds__(256) void k3_ctx(
    const unsigned short* __restrict__ aggb, const float* __restrict__ cw,
    float* __restrict__ wraw)
{
    __shared__ float sA[64 * 68];
    __shared__ float sW[64 * 68];
    const int t = threadIdx.x;
    const int b = blockIdx.z;
    const int d0 = blockIdx.x * 64;
    const int l0 = blockIdx.y * 64;
    const unsigned short* ab = aggb + (size_t)b * 2048 * 192;
    const int ti = t >> 4, tj = t & 15;
    float acc[4][4] = {{0.f}};

    for (int o0 = 0; o0 < 2048; o0 += 64) {
        for (int i = t; i < 4096; i += 256) {
            int oo = i >> 6, dd = i & 63;
            sA[oo * 68 + dd] = bf2f(ab[(size_t)(o0 + oo) * 192 + d0 + dd]);
            sW[oo * 68 + dd] = cw[(size_t)(o0 + oo) * 192 + l0 + dd];
        }
        __syncthreads();
        for (int o = 0; o < 64; ++o) {
            const float* ap = sA + o * 68 + ti * 4;
            const float* wp = sW + o * 68 + tj * 4;
            float a0 = ap[0], a1 = ap[1], a2 = ap[2], a3 = ap[3];
            float w0 = wp[0], w1v = wp[1], w2v = wp[2], w3 = wp[3];
            acc[0][0] = fmaf(a0, w0, acc[0][0]); acc[0][1] = fmaf(a0, w1v, acc[0][1]);
            acc[0][2] = fmaf(a0, w2v, acc[0][2]); acc[0][3] = fmaf(a0, w3, acc[0][3]);
            acc[1][0] = fmaf(a1, w0, acc[1][0]); acc[1][1] = fmaf(a1, w1v, acc[1][1]);
            acc[1][2] = fmaf(a1, w2v, acc[1][2]); acc[1][3] = fmaf(a1, w3, acc[1][3]);
            acc[2][0] = fmaf(a2, w0, acc[2][0]); acc[2][1] = fmaf(a2, w1v, acc[2][1]);
            acc[2][2] = fmaf(a2, w2v, acc[2][2]); acc[2][3] = fmaf(a2, w3, acc[2][3]);
            acc[3][0] = fmaf(a3, w0, acc[3][0]); acc[3][1] = fmaf(a3, w1v, acc[3][1]);
            acc[3][2] = fmaf(a3, w2v, acc[3][2]); acc[3][3] = fmaf(a3, w3, acc[3][3]);
        }
        __syncthreads();
    }
    float* wb = wraw + (size_t)b * 36864;
    #pragma unroll
    for (int i = 0; i < 4; ++i)
        #pragma unroll
        for (int j = 0; j < 4; ++j)
            wb[(d0 + ti * 4 + i) * 192 + l0 + tj * 4 + j] = tanhf(acc[i][j]);
}

// ---------------------------------------------------------------------------
__global__ __launch_bounds__(192) void k3b_m2(
    const float* __restrict__ wmat, const float* __restrict__ wl,
    float* __restrict__ m2)
{
    const int t = threadIdx.x;
    const int b = blockIdx.y;
    const int d = blockIdx.x * 2 + (t / 96);
    const int l = t % 96;
    const float* wrow = wmat + (size_t)b * 36864 + d * 192;
    float acc = wl[d * 96 + l];
    for (int k = 0; k < 192; ++k)
        acc = fmaf(wrow[k], wl[k * 96 + l], acc);
    m2[(size_t)b * 18432 + d * 96 + l] = acc;
}

// ---------------------------------------------------------------------------
// k4_tiled: out = gcn@M2 + bl. 64 rows x 96 cols per block (grid 32x16,
// 192 thr). m2 staged once in LDS (73.7 KB -> 2 blocks/CU). Thread tile
// 4 rows x 8 cols; x read from global (lane-broadcast), ext from vt
// (uniform channel, consecutive c -> coalesced u16).
// ---------------------------------------------------------------------------
__global__ __launch_bounds__(192) void k4_tiled(
    const float* __restrict__ x, const unsigned short* __restrict__ vt,
    const float* __restrict__ m2, const float* __restrict__ bl,
    float* __restrict__ out)
{
    __shared__ float sm2[192 * 96];
    const int t = threadIdx.x;           // 0..191
    const int rblk = blockIdx.x;         // 0..31
    const int b = blockIdx.y;
    // stage m2 (4608 float4, 24 per thread)
    {
        const float4* src = (const float4*)(m2 + (size_t)b * 18432);
        float4* dst = (float4*)sm2;
        #pragma unroll
        for (int i = 0; i < 24; ++i) dst[t + i * 192] = src[t + i * 192];
    }
    __syncthreads();

    const int rg = t / 12;               // 0..15
    const int cg = t % 12;               // 0..11
    const int j0 = cg * 8;
    const int cloc = rblk * 64 + rg * 4; // within-batch row
    const int rr = b * 2048 + cloc;      // global row
    float acc[4][8];
    #pragma unroll
    for (int i = 0; i < 4; ++i)
        #pragma unroll
        for (int j = 0; j < 8; ++j) acc[i][j] = bl[j0 + j];

    // x part: k = 0..127 in chunks of 8
    for (int k0 = 0; k0 < 128; k0 += 8) {
        float rv[4][8];
        #pragma unroll
        for (int i = 0; i < 4; ++i) {
            const float4* xr = (const float4*)(x + (size_t)(rr + i) * 128 + k0);
            float4 a = xr[0], c4 = xr[1];
            rv[i][0] = a.x; rv[i][1] = a.y; rv[i][2] = a.z; rv[i][3] = a.w;
            rv[i][4] = c4.x; rv[i][5] = c4.y; rv[i][6] = c4.z; rv[i][7] = c4.w;
        }
        #pragma unroll
        for (int kk = 0; kk < 8; ++kk) {
            const float* mr = sm2 + (k0 + kk) * 96 + j0;
            float mv[8];
            #pragma unroll
            for (int j = 0; j < 8; ++j) mv[j] = mr[j];
            #pragma unroll
            for (int i = 0; i < 4; ++i)
                #pragma unroll
                for (int j = 0; j < 8; ++j)
                    acc[i][j] = fmaf(rv[i][kk], mv[j], acc[i][j]);
        }
    }
    // ext part: k = 128..191, per-k u16 loads (uniform channel, coalesced c)
    for (int k = 128; k < 192; ++k) {
        const unsigned short* vr = vt + (size_t)(b * 192 + k) * 2048 + cloc;
        float rv0 = bf2f(vr[0]), rv1 = bf2f(vr[1]);
        float rv2 = bf2f(vr[2]), rv3 = bf2f(vr[3]);
        const float* mr = sm2 + k * 96 + j0;
        #pragma unroll
        for (int j = 0; j < 8; ++j) {
            float mv = mr[j];
            acc[0][j] = fmaf(rv0, mv, acc[0][j]);
            acc[1][j] = fmaf(rv1, mv, acc[1][j]);
            acc[2][j] = fmaf(rv2, mv, acc[2][j]);
            acc[3][j] = fmaf(rv3, mv, acc[3][j]);
        }
    }
    #pragma unroll
    for (int i = 0; i < 4; ++i) {
        float* orow = out + (size_t)(rr + i) * 96 + j0;
        *(float4*)orow = make_float4(acc[i][0], acc[i][1], acc[i][2], acc[i][3]);
        *(float4*)(orow + 4) = make_float4(acc[i][4], acc[i][5], acc[i][6], acc[i][7]);
    }
}

// ---------------------------------------------------------------------------
extern "C" void kernel_launch(void* const* d_in, const int* in_sizes, int n_in,
                              void* d_out, int out_size, void* d_ws, size_t ws_size,
                              hipStream_t stream) {
    const float* x      = (const float*)d_in[0];
    const float* id_emb = (const float*)d_in[1];
    const float* w1     = (const float*)d_in[2];
    const float* b1     = (const float*)d_in[3];
    const float* w2     = (const float*)d_in[4];
    const float* b2     = (const float*)d_in[5];
    const float* ce     = (const float*)d_in[6];
    const float* wic    = (const float*)d_in[7];
    const float* bic    = (const float*)d_in[8];
    const float* wg     = (const float*)d_in[9];
    const float* bg     = (const float*)d_in[10];
    const float* cw     = (const float*)d_in[11];
    const float* wl     = (const float*)d_in[12];
    const float* bl     = (const float*)d_in[13];
    float* out = (float*)d_out;

    float* ws = (float*)d_ws;
    unsigned short* vt    = (unsigned short*)ws;             // 3,145,728 f-eq
    unsigned short* geb16 = (unsigned short*)(ws + 3145728); //   524,288 f-eq
    unsigned short* aggb  = (unsigned short*)(ws + 3670016); // 3,145,728 f-eq
    float* wraw  = ws + 6815744;                             //   589,824
    float* m2    = ws + 7405568;                             //   294,912
    float* sumv  = ws + 7700480;                             //     3,072
    float* wpart = ws + 7703552;                             // 4,718,592 (opt)
    const size_t need_sk = (7703552ull + 4718592ull) * 4ull; // 49.7 MB
    const bool use_sk = (ws_size >= need_sk);

    hipLaunchKernelGGL(k0_transpose_x, dim3(32, 16), dim3(256), 0, stream, x, vt);
    hipLaunchKernelGGL(k1_tiled, dim3(1024), dim3(256), 0, stream,
                       x, id_emb, w1, b1, w2, b2, ce, wic, bic, wg, bg, vt, geb16);
    hipLaunchKernelGGL(k1b_sumv, dim3(192, 16), dim3(256), 0, stream, vt, sumv);
    hipLaunchKernelGGL(k2_fused, dim3(32, 16), dim3(256), 0, stream,
                       geb16, vt, sumv, aggb);
    if (use_sk) {
        hipLaunchKernelGGL(k3_ctx_sk, dim3(3, 3, 128), dim3(256), 0, stream,
                           aggb, cw, wpart);
        hipLaunchKernelGGL(k3r_reduce, dim3(144, 16), dim3(256), 0, stream,
                           wpart, wraw);
    } else {
        hipLaunchKernelGGL(k3_ctx, dim3(3, 3, 16), dim3(256), 0, stream,
                           aggb, cw, wraw);
    }
    hipLaunchKernelGGL(k3b_m2, dim3(96, 16), dim3(192), 0, stream,
                       wraw, wl, m2);
    hipLaunchKernelGGL(k4_tiled, dim3(32, 16), dim3(192), 0, stream,
                       x, vt, m2, bl, out);
}